// Round 1
// baseline (424.116 us; speedup 1.0000x reference)
//
#include <hip/hip_runtime.h>
#include <hip/hip_bf16.h>

typedef unsigned short u16;
typedef unsigned int u32;
typedef __attribute__((ext_vector_type(8))) short bfrag;   // 8 bf16 (4 VGPRs)
typedef __attribute__((ext_vector_type(4))) float f32x4;

#define DEVINL __device__ __forceinline__

DEVINL u16 f2bf(float f) {
  u32 u = __float_as_uint(f);
  u32 r = (u + 0x7fffu + ((u >> 16) & 1u)) >> 16;   // RNE
  return (u16)r;
}
DEVINL float bf2f(u16 u) { return __uint_as_float(((u32)u) << 16); }
DEVINL u32 pack2(float lo, float hi) { return (u32)f2bf(lo) | ((u32)f2bf(hi) << 16); }

DEVINL void gload_lds16(const void* g, void* l) {
  __builtin_amdgcn_global_load_lds(
      (const __attribute__((address_space(1))) void*)g,
      (__attribute__((address_space(3))) void*)l, 16, 0, 0);
}

DEVINL void storeC(u16* C, size_t idx, float v) { C[idx] = f2bf(v); }
DEVINL void storeC(float* C, size_t idx, float v) { C[idx] = v; }

// ---------------- prep kernels ----------------

__global__ void cast_v4(const float* __restrict__ in, u16* __restrict__ out, int n4) {
  const int i = blockIdx.x * 256 + threadIdx.x;
  if (i < n4) {
    const float4 f = ((const float4*)in)[i];
    uint2 r;
    r.x = pack2(f.x, f.y);
    r.y = pack2(f.z, f.w);
    ((uint2*)out)[i] = r;
  }
}

__global__ void pack_mask(const int* __restrict__ mask, u32* __restrict__ bits) {
  const size_t wi = (size_t)blockIdx.x * 256 + threadIdx.x;
  const int* src = mask + wi * 32;
  u32 v = 0;
#pragma unroll
  for (int i = 0; i < 8; ++i) {
    const int4 m4 = ((const int4*)src)[i];
    if (m4.x) v |= 1u << (i * 4 + 0);
    if (m4.y) v |= 1u << (i * 4 + 1);
    if (m4.z) v |= 1u << (i * 4 + 2);
    if (m4.w) v |= 1u << (i * 4 + 3);
  }
  bits[wi] = v;
}

// ---------------- GEMM: C[M,N] = A[M,K] @ W[N,K]^T + bias ----------------
// 128x128 tile, BK=64, 4 waves (2x2), each wave 64x64 = 4x4 frags of 16x16x32.

template <typename OutT>
__global__ __launch_bounds__(256) void gemm_bt_a16(
    const u16* __restrict__ A, const u16* __restrict__ W,
    const float* __restrict__ bias, OutT* __restrict__ C,
    int M, int N, int K) {
  __shared__ u16 sA[128 * 64];
  __shared__ u16 sB[128 * 64];
  const int t = threadIdx.x;
  const int w = t >> 6, lane = t & 63;
  const int lr = lane & 15, lk = (lane >> 4) * 8;
  const int m0 = blockIdx.x * 128, n0 = blockIdx.y * 128;
  const int wr = (w >> 1) * 64, wc = (w & 1) * 64;
  f32x4 acc[4][4] = {};

  for (int k0 = 0; k0 < K; k0 += 64) {
#pragma unroll
    for (int i = 0; i < 4; ++i) {
      const int idx = i * 256 + t;
      const int row = idx >> 3;
      const int col = (idx & 7) * 8;
      gload_lds16(A + (size_t)(m0 + row) * K + k0 + col, &sA[idx * 8]);
      gload_lds16(W + (size_t)(n0 + row) * K + k0 + col, &sB[idx * 8]);
    }
    __syncthreads();
#pragma unroll
    for (int ks = 0; ks < 2; ++ks) {
      bfrag av[4], bv[4];
#pragma unroll
      for (int m = 0; m < 4; ++m)
        av[m] = *(const bfrag*)&sA[(wr + m * 16 + lr) * 64 + ks * 32 + lk];
#pragma unroll
      for (int n = 0; n < 4; ++n)
        bv[n] = *(const bfrag*)&sB[(wc + n * 16 + lr) * 64 + ks * 32 + lk];
#pragma unroll
      for (int m = 0; m < 4; ++m)
#pragma unroll
        for (int n = 0; n < 4; ++n)
          acc[m][n] = __builtin_amdgcn_mfma_f32_16x16x32_bf16(av[m], bv[n], acc[m][n], 0, 0, 0);
    }
    __syncthreads();
  }

  const int orow = (lane >> 4) * 4;
#pragma unroll
  for (int m = 0; m < 4; ++m) {
#pragma unroll
    for (int n = 0; n < 4; ++n) {
      const int r = m0 + wr + m * 16 + orow;
      const int c = n0 + wc + n * 16 + lr;
      const float bz = bias[c];
#pragma unroll
      for (int j = 0; j < 4; ++j)
        storeC(C, (size_t)(r + j) * N + c, acc[m][n][j] + bz);
    }
  }
}

template <typename OutT>
__global__ __launch_bounds__(256) void gemm_bt_a32(
    const float* __restrict__ A, const u16* __restrict__ W,
    const float* __restrict__ bias, OutT* __restrict__ C,
    int M, int N, int K) {
  __shared__ u16 sA[128 * 64];
  __shared__ u16 sB[128 * 64];
  const int t = threadIdx.x;
  const int w = t >> 6, lane = t & 63;
  const int lr = lane & 15, lk = (lane >> 4) * 8;
  const int m0 = blockIdx.x * 128, n0 = blockIdx.y * 128;
  const int wr = (w >> 1) * 64, wc = (w & 1) * 64;
  f32x4 acc[4][4] = {};

  for (int k0 = 0; k0 < K; k0 += 64) {
#pragma unroll
    for (int i = 0; i < 4; ++i) {
      const int idx = i * 256 + t;
      const int row = idx >> 3;
      const int col = (idx & 7) * 8;
      const float* src = A + (size_t)(m0 + row) * K + k0 + col;
      const float4 f0 = *(const float4*)src;
      const float4 f1 = *(const float4*)(src + 4);
      u16 tmp[8] = {f2bf(f0.x), f2bf(f0.y), f2bf(f0.z), f2bf(f0.w),
                    f2bf(f1.x), f2bf(f1.y), f2bf(f1.z), f2bf(f1.w)};
      *(bfrag*)&sA[idx * 8] = *(bfrag*)tmp;  // one ds_write_b128
      gload_lds16(W + (size_t)(n0 + row) * K + k0 + col, &sB[idx * 8]);
    }
    __syncthreads();
#pragma unroll
    for (int ks = 0; ks < 2; ++ks) {
      bfrag av[4], bv[4];
#pragma unroll
      for (int m = 0; m < 4; ++m)
        av[m] = *(const bfrag*)&sA[(wr + m * 16 + lr) * 64 + ks * 32 + lk];
#pragma unroll
      for (int n = 0; n < 4; ++n)
        bv[n] = *(const bfrag*)&sB[(wc + n * 16 + lr) * 64 + ks * 32 + lk];
#pragma unroll
      for (int m = 0; m < 4; ++m)
#pragma unroll
        for (int n = 0; n < 4; ++n)
          acc[m][n] = __builtin_amdgcn_mfma_f32_16x16x32_bf16(av[m], bv[n], acc[m][n], 0, 0, 0);
    }
    __syncthreads();
  }

  const int orow = (lane >> 4) * 4;
#pragma unroll
  for (int m = 0; m < 4; ++m) {
#pragma unroll
    for (int n = 0; n < 4; ++n) {
      const int r = m0 + wr + m * 16 + orow;
      const int c = n0 + wc + n * 16 + lr;
      const float bz = bias[c];
#pragma unroll
      for (int j = 0; j < 4; ++j)
        storeC(C, (size_t)(r + j) * N + c, acc[m][n][j] + bz);
    }
  }
}

// ---------------- attention ----------------
// block = (b, h, 64-row q-tile); 4 waves, wave w owns q-rows [w*16, w*16+16).
// scores = (Q.K^T)/sqrt(128) + pos[h] ; mask==0 -> -1e9 ; online softmax ; O = P.V

__global__ __launch_bounds__(256) void attn_fwd(
    const u16* __restrict__ Qm, const u16* __restrict__ Km,
    const u16* __restrict__ Vm, const u16* __restrict__ posb,
    const u32* __restrict__ mbits, u16* __restrict__ Om) {
  const int b = blockIdx.x >> 4;
  const int qt = blockIdx.x & 15;
  const int h = blockIdx.y;
  const int t = threadIdx.x;
  const int w = t >> 6, lane = t & 63;
  const int lr = lane & 15, lg = lane >> 4;

  __shared__ u16 sQ[64 * 64];
  __shared__ u16 sK[64 * 64];
  __shared__ u16 sVt[64 * 64];   // transposed: sVt[dk][k]
  __shared__ u16 sP[4][16 * 64];

  const int q0 = qt * 64;
  const size_t base = ((size_t)b * 1024) * 1024 + (size_t)h * 64;  // [B,S,D] row base for this (b,h)

#pragma unroll
  for (int i = 0; i < 2; ++i) {
    const int idx = i * 256 + t;
    const int row = idx >> 3;
    const int col = (idx & 7) * 8;
    gload_lds16(Qm + base + (size_t)(q0 + row) * 1024 + col, &sQ[idx * 8]);
  }

  f32x4 o[4] = {};
  float mrow[4], lrow[4];
#pragma unroll
  for (int j = 0; j < 4; ++j) { mrow[j] = -3.0e38f; lrow[j] = 0.f; }
  const float scl = 0.0883883476483184f;  // 1/sqrt(2*dk) = 1/sqrt(128)

  for (int kt = 0; kt < 16; ++kt) {
    const int k0 = kt * 64;
    __syncthreads();   // previous iter done with sK/sVt
#pragma unroll
    for (int i = 0; i < 2; ++i) {
      const int idx = i * 256 + t;
      const int row = idx >> 3;
      const int col = (idx & 7) * 8;
      gload_lds16(Km + base + (size_t)(k0 + row) * 1024 + col, &sK[idx * 8]);
      union { uint4 u; u16 s[8]; } vv;
      vv.u = *(const uint4*)(Vm + base + (size_t)(k0 + row) * 1024 + col);
#pragma unroll
      for (int j = 0; j < 8; ++j) sVt[(col + j) * 64 + row] = vv.s[j];
    }
    __syncthreads();

    // QK^T: S_tile[16q][64k] per wave
    f32x4 s[4] = {};
#pragma unroll
    for (int ks = 0; ks < 2; ++ks) {
      const bfrag aq = *(const bfrag*)&sQ[(w * 16 + lr) * 64 + ks * 32 + lg * 8];
#pragma unroll
      for (int n = 0; n < 4; ++n) {
        const bfrag bk = *(const bfrag*)&sK[(n * 16 + lr) * 64 + ks * 32 + lg * 8];
        s[n] = __builtin_amdgcn_mfma_f32_16x16x32_bf16(aq, bk, s[n], 0, 0, 0);
      }
    }

    // scale + positional bias + mask
    float p[4][4];
#pragma unroll
    for (int n = 0; n < 4; ++n) {
      const int kc = k0 + n * 16 + lr;
#pragma unroll
      for (int j = 0; j < 4; ++j) {
        const int qr = q0 + w * 16 + lg * 4 + j;
        float sv = s[n][j] * scl + bf2f(posb[((size_t)h * 1024 + qr) * 1024 + kc]);
        const u32 mw = mbits[((size_t)b * 1024 + qr) * 32 + (kc >> 5)];
        if (!((mw >> (kc & 31)) & 1u)) sv = -1.0e9f;
        p[n][j] = sv;
      }
    }

    // online softmax (row stats via 16-lane butterfly; row j lives in this lane-group)
#pragma unroll
    for (int j = 0; j < 4; ++j) {
      float tm = fmaxf(fmaxf(p[0][j], p[1][j]), fmaxf(p[2][j], p[3][j]));
      tm = fmaxf(tm, __shfl_xor(tm, 1));
      tm = fmaxf(tm, __shfl_xor(tm, 2));
      tm = fmaxf(tm, __shfl_xor(tm, 4));
      tm = fmaxf(tm, __shfl_xor(tm, 8));
      const float mn = fmaxf(mrow[j], tm);
      const float sc = __expf(mrow[j] - mn);
      float rs = 0.f;
#pragma unroll
      for (int n = 0; n < 4; ++n) { p[n][j] = __expf(p[n][j] - mn); rs += p[n][j]; }
      rs += __shfl_xor(rs, 1);
      rs += __shfl_xor(rs, 2);
      rs += __shfl_xor(rs, 4);
      rs += __shfl_xor(rs, 8);
      lrow[j] = lrow[j] * sc + rs;
      mrow[j] = mn;
#pragma unroll
      for (int n = 0; n < 4; ++n) o[n][j] *= sc;
    }

    // P -> per-wave LDS (bf16), then PV
#pragma unroll
    for (int n = 0; n < 4; ++n)
#pragma unroll
      for (int j = 0; j < 4; ++j)
        sP[w][(lg * 4 + j) * 64 + n * 16 + lr] = f2bf(p[n][j]);

#pragma unroll
    for (int ks = 0; ks < 2; ++ks) {
      const bfrag ap = *(const bfrag*)&sP[w][lr * 64 + ks * 32 + lg * 8];
#pragma unroll
      for (int n = 0; n < 4; ++n) {
        const bfrag bvf = *(const bfrag*)&sVt[(n * 16 + lr) * 64 + ks * 32 + lg * 8];
        o[n] = __builtin_amdgcn_mfma_f32_16x16x32_bf16(ap, bvf, o[n], 0, 0, 0);
      }
    }
  }

  // normalize + write x_attn[b, q, h*64 + d] (bf16)
#pragma unroll
  for (int n = 0; n < 4; ++n) {
#pragma unroll
    for (int j = 0; j < 4; ++j) {
      const int qr = q0 + w * 16 + lg * 4 + j;
      Om[base + (size_t)qr * 1024 + n * 16 + lr] = f2bf(o[n][j] / lrow[j]);
    }
  }
}

// ---------------- launch ----------------

extern "C" void kernel_launch(void* const* d_in, const int* in_sizes, int n_in,
                              void* d_out, int out_size, void* d_ws, size_t ws_size,
                              hipStream_t stream) {
  const float* query = (const float*)d_in[0];
  const float* key_  = (const float*)d_in[1];
  const float* value = (const float*)d_in[2];
  const int*   mask  = (const int*)d_in[3];
  const float* pos   = (const float*)d_in[4];
  const float* wq = (const float*)d_in[5];
  const float* bq = (const float*)d_in[6];
  const float* wk = (const float*)d_in[7];
  const float* bk = (const float*)d_in[8];
  const float* wv = (const float*)d_in[9];
  const float* bv = (const float*)d_in[10];
  const float* wo = (const float*)d_in[11];
  const float* bo = (const float*)d_in[12];

  char* ws = (char*)d_ws;
  const size_t MB = 1024 * 1024;
  u16* wqb  = (u16*)(ws + 0 * MB);     // 2MB each
  u16* wkb  = (u16*)(ws + 2 * MB);
  u16* wvb  = (u16*)(ws + 4 * MB);
  u16* wob  = (u16*)(ws + 6 * MB);
  u16* posb = (u16*)(ws + 8 * MB);     // 32MB  [H,S,S] bf16
  u16* Qb   = (u16*)(ws + 40 * MB);    // 16MB  [B*S, D] bf16
  u16* Kb   = (u16*)(ws + 56 * MB);
  u16* Vb   = (u16*)(ws + 72 * MB);
  u16* Xa   = (u16*)(ws + 88 * MB);    // attention out
  u32* mb   = (u32*)(ws + 104 * MB);   // 1MB bitmask
  u16* Y1   = Qb;                      // reuse Q buffer (dead after attention)

  cast_v4<<<1024, 256, 0, stream>>>(wq, wqb, 262144);
  cast_v4<<<1024, 256, 0, stream>>>(wk, wkb, 262144);
  cast_v4<<<1024, 256, 0, stream>>>(wv, wvb, 262144);
  cast_v4<<<1024, 256, 0, stream>>>(wo, wob, 262144);
  cast_v4<<<16384, 256, 0, stream>>>(pos, posb, 4194304);
  pack_mask<<<1024, 256, 0, stream>>>(mask, mb);

  const dim3 gg(64, 8);
  gemm_bt_a32<u16><<<gg, 256, 0, stream>>>(query, wqb, bq, Qb, 8192, 1024, 1024);
  gemm_bt_a32<u16><<<gg, 256, 0, stream>>>(key_,  wkb, bk, Kb, 8192, 1024, 1024);
  gemm_bt_a32<u16><<<gg, 256, 0, stream>>>(value, wvb, bv, Vb, 8192, 1024, 1024);

  attn_fwd<<<dim3(128, 16), 256, 0, stream>>>(Qb, Kb, Vb, posb, mb, Xa);

  gemm_bt_a16<u16><<<gg, 256, 0, stream>>>(Xa, wob, bo, Y1, 8192, 1024, 1024);
  gemm_bt_a16<float><<<gg, 256, 0, stream>>>(Y1, wob, bo, (float*)d_out, 8192, 1024, 1024);
}

// Round 2
// 344.929 us; speedup vs baseline: 1.2296x; 1.2296x over previous
//
#include <hip/hip_runtime.h>
#include <hip/hip_bf16.h>

typedef unsigned short u16;
typedef unsigned int u32;
typedef __attribute__((ext_vector_type(8))) short bfrag;   // 8 bf16 (4 VGPRs)
typedef __attribute__((ext_vector_type(4))) float f32x4;

#define DEVINL __device__ __forceinline__

DEVINL u16 f2bf(float f) {
  u32 u = __float_as_uint(f);
  u32 r = (u + 0x7fffu + ((u >> 16) & 1u)) >> 16;   // RNE
  return (u16)r;
}
DEVINL float bf2f(u16 u) { return __uint_as_float(((u32)u) << 16); }
DEVINL u32 pack2(float lo, float hi) { return (u32)f2bf(lo) | ((u32)f2bf(hi) << 16); }

DEVINL void gload_lds16(const void* g, void* l) {
  __builtin_amdgcn_global_load_lds(
      (const __attribute__((address_space(1))) void*)g,
      (__attribute__((address_space(3))) void*)l, 16, 0, 0);
}

DEVINL void storeC(u16* C, size_t idx, float v) { C[idx] = f2bf(v); }
DEVINL void storeC(float* C, size_t idx, float v) { C[idx] = v; }

// ---------------- prep kernels ----------------

__global__ void cast_v4(const float* __restrict__ in, u16* __restrict__ out, int n4) {
  const int i = blockIdx.x * 256 + threadIdx.x;
  if (i < n4) {
    const float4 f = ((const float4*)in)[i];
    uint2 r;
    r.x = pack2(f.x, f.y);
    r.y = pack2(f.z, f.w);
    ((uint2*)out)[i] = r;
  }
}

__global__ void pack_mask(const int* __restrict__ mask, u32* __restrict__ bits) {
  const size_t wi = (size_t)blockIdx.x * 256 + threadIdx.x;
  const int* src = mask + wi * 32;
  u32 v = 0;
#pragma unroll
  for (int i = 0; i < 8; ++i) {
    const int4 m4 = ((const int4*)src)[i];
    if (m4.x) v |= 1u << (i * 4 + 0);
    if (m4.y) v |= 1u << (i * 4 + 1);
    if (m4.z) v |= 1u << (i * 4 + 2);
    if (m4.w) v |= 1u << (i * 4 + 3);
  }
  bits[wi] = v;
}

// transpose-cast: out[j][k] = bf16(in[k][j]), 1024x1024, grid(16,16), 256 thr
__global__ void transpose_cast(const float* __restrict__ in, u16* __restrict__ out) {
  __shared__ u16 tile[64][65];
  const int t = threadIdx.x;
  const int bx = blockIdx.x, by = blockIdx.y;
#pragma unroll
  for (int p = 0; p < 4; ++p) {
    const int r = (t >> 4) + p * 16;
    const int c = (t & 15) * 4;
    const float4 f = *(const float4*)&in[(size_t)(by * 64 + r) * 1024 + bx * 64 + c];
    tile[c + 0][r] = f2bf(f.x);
    tile[c + 1][r] = f2bf(f.y);
    tile[c + 2][r] = f2bf(f.z);
    tile[c + 3][r] = f2bf(f.w);
  }
  __syncthreads();
#pragma unroll
  for (int p = 0; p < 4; ++p) {
    const int r = (t >> 4) + p * 16;
    const int c = (t & 15) * 4;
    uint2 v;
    v.x = (u32)tile[r][c] | ((u32)tile[r][c + 1] << 16);
    v.y = (u32)tile[r][c + 2] | ((u32)tile[r][c + 3] << 16);
    *(uint2*)&out[(size_t)(bx * 64 + r) * 1024 + by * 64 + c] = v;
  }
}

// bo2 = Wo @ bo + bo ; one wave per output row
__global__ void bias2(const float* __restrict__ wo, const float* __restrict__ bo,
                      float* __restrict__ bo2) {
  const int w = threadIdx.x >> 6, lane = threadIdx.x & 63;
  const int row = blockIdx.x * 4 + w;
  const float* src = wo + (size_t)row * 1024;
  float s = 0.f;
#pragma unroll
  for (int i = 0; i < 4; ++i) {
    const float4 f = *(const float4*)&src[lane * 4 + i * 256];
    const float4 g = *(const float4*)&bo[lane * 4 + i * 256];
    s += f.x * g.x + f.y * g.y + f.z * g.z + f.w * g.w;
  }
#pragma unroll
  for (int d = 1; d < 64; d <<= 1) s += __shfl_xor(s, d);
  if (lane == 0) bo2[row] = s + bo[row];
}

// ---------------- GEMM: C[M,N] = (A[M,K] @ W[N,K]^T + bias) * oscale ----------------
// 128x128 tile, BK=64, 4 waves (2x2), each wave 64x64 = 4x4 frags of 16x16x32.

template <typename OutT>
__global__ __launch_bounds__(256) void gemm_bt_a16(
    const u16* __restrict__ A, const u16* __restrict__ W,
    const float* __restrict__ bias, OutT* __restrict__ C,
    int M, int N, int K) {
  __shared__ u16 sA[128 * 64];
  __shared__ u16 sB[128 * 64];
  const int t = threadIdx.x;
  const int w = t >> 6, lane = t & 63;
  const int lr = lane & 15, lk = (lane >> 4) * 8;
  const int m0 = blockIdx.x * 128, n0 = blockIdx.y * 128;
  const int wr = (w >> 1) * 64, wc = (w & 1) * 64;
  f32x4 acc[4][4] = {};

  for (int k0 = 0; k0 < K; k0 += 64) {
#pragma unroll
    for (int i = 0; i < 4; ++i) {
      const int idx = i * 256 + t;
      const int row = idx >> 3;
      const int col = (idx & 7) * 8;
      gload_lds16(A + (size_t)(m0 + row) * K + k0 + col, &sA[idx * 8]);
      gload_lds16(W + (size_t)(n0 + row) * K + k0 + col, &sB[idx * 8]);
    }
    __syncthreads();
#pragma unroll
    for (int ks = 0; ks < 2; ++ks) {
      bfrag av[4], bv[4];
#pragma unroll
      for (int m = 0; m < 4; ++m)
        av[m] = *(const bfrag*)&sA[(wr + m * 16 + lr) * 64 + ks * 32 + lk];
#pragma unroll
      for (int n = 0; n < 4; ++n)
        bv[n] = *(const bfrag*)&sB[(wc + n * 16 + lr) * 64 + ks * 32 + lk];
#pragma unroll
      for (int m = 0; m < 4; ++m)
#pragma unroll
        for (int n = 0; n < 4; ++n)
          acc[m][n] = __builtin_amdgcn_mfma_f32_16x16x32_bf16(av[m], bv[n], acc[m][n], 0, 0, 0);
    }
    __syncthreads();
  }

  const int orow = (lane >> 4) * 4;
#pragma unroll
  for (int m = 0; m < 4; ++m) {
#pragma unroll
    for (int n = 0; n < 4; ++n) {
      const int r = m0 + wr + m * 16 + orow;
      const int c = n0 + wc + n * 16 + lr;
      const float bz = bias[c];
#pragma unroll
      for (int j = 0; j < 4; ++j)
        storeC(C, (size_t)(r + j) * N + c, acc[m][n][j] + bz);
    }
  }
}

// A fp32 (cast to bf16 on stage); optional output scale
template <typename OutT>
__global__ __launch_bounds__(256) void gemm_bt_a32(
    const float* __restrict__ A, const u16* __restrict__ W,
    const float* __restrict__ bias, OutT* __restrict__ C,
    int M, int N, int K, float oscale) {
  __shared__ u16 sA[128 * 64];
  __shared__ u16 sB[128 * 64];
  const int t = threadIdx.x;
  const int w = t >> 6, lane = t & 63;
  const int lr = lane & 15, lk = (lane >> 4) * 8;
  const int m0 = blockIdx.x * 128, n0 = blockIdx.y * 128;
  const int wr = (w >> 1) * 64, wc = (w & 1) * 64;
  f32x4 acc[4][4] = {};

  for (int k0 = 0; k0 < K; k0 += 64) {
#pragma unroll
    for (int i = 0; i < 4; ++i) {
      const int idx = i * 256 + t;
      const int row = idx >> 3;
      const int col = (idx & 7) * 8;
      const float* src = A + (size_t)(m0 + row) * K + k0 + col;
      const float4 f0 = *(const float4*)src;
      const float4 f1 = *(const float4*)(src + 4);
      u16 tmp[8] = {f2bf(f0.x), f2bf(f0.y), f2bf(f0.z), f2bf(f0.w),
                    f2bf(f1.x), f2bf(f1.y), f2bf(f1.z), f2bf(f1.w)};
      *(bfrag*)&sA[idx * 8] = *(bfrag*)tmp;
      gload_lds16(W + (size_t)(n0 + row) * K + k0 + col, &sB[idx * 8]);
    }
    __syncthreads();
#pragma unroll
    for (int ks = 0; ks < 2; ++ks) {
      bfrag av[4], bv[4];
#pragma unroll
      for (int m = 0; m < 4; ++m)
        av[m] = *(const bfrag*)&sA[(wr + m * 16 + lr) * 64 + ks * 32 + lk];
#pragma unroll
      for (int n = 0; n < 4; ++n)
        bv[n] = *(const bfrag*)&sB[(wc + n * 16 + lr) * 64 + ks * 32 + lk];
#pragma unroll
      for (int m = 0; m < 4; ++m)
#pragma unroll
        for (int n = 0; n < 4; ++n)
          acc[m][n] = __builtin_amdgcn_mfma_f32_16x16x32_bf16(av[m], bv[n], acc[m][n], 0, 0, 0);
    }
    __syncthreads();
  }

  const int orow = (lane >> 4) * 4;
#pragma unroll
  for (int m = 0; m < 4; ++m) {
#pragma unroll
    for (int n = 0; n < 4; ++n) {
      const int r = m0 + wr + m * 16 + orow;
      const int c = n0 + wc + n * 16 + lr;
      const float bz = bias[c];
#pragma unroll
      for (int j = 0; j < 4; ++j)
        storeC(C, (size_t)(r + j) * N + c, (acc[m][n][j] + bz) * oscale);
    }
  }
}

// V projection writing transposed output Vt[((b*16+h)*64 + d)*1024 + s]
__global__ __launch_bounds__(256) void gemm_bt_a32_vt(
    const float* __restrict__ A, const u16* __restrict__ W,
    const float* __restrict__ bias, u16* __restrict__ Vt,
    int M, int N, int K) {
  __shared__ u16 sA[128 * 64];
  __shared__ u16 sB[128 * 64];
  const int t = threadIdx.x;
  const int w = t >> 6, lane = t & 63;
  const int lr = lane & 15, lk = (lane >> 4) * 8;
  const int m0 = blockIdx.x * 128, n0 = blockIdx.y * 128;
  const int wr = (w >> 1) * 64, wc = (w & 1) * 64;
  f32x4 acc[4][4] = {};

  for (int k0 = 0; k0 < K; k0 += 64) {
#pragma unroll
    for (int i = 0; i < 4; ++i) {
      const int idx = i * 256 + t;
      const int row = idx >> 3;
      const int col = (idx & 7) * 8;
      const float* src = A + (size_t)(m0 + row) * K + k0 + col;
      const float4 f0 = *(const float4*)src;
      const float4 f1 = *(const float4*)(src + 4);
      u16 tmp[8] = {f2bf(f0.x), f2bf(f0.y), f2bf(f0.z), f2bf(f0.w),
                    f2bf(f1.x), f2bf(f1.y), f2bf(f1.z), f2bf(f1.w)};
      *(bfrag*)&sA[idx * 8] = *(bfrag*)tmp;
      gload_lds16(W + (size_t)(n0 + row) * K + k0 + col, &sB[idx * 8]);
    }
    __syncthreads();
#pragma unroll
    for (int ks = 0; ks < 2; ++ks) {
      bfrag av[4], bv[4];
#pragma unroll
      for (int m = 0; m < 4; ++m)
        av[m] = *(const bfrag*)&sA[(wr + m * 16 + lr) * 64 + ks * 32 + lk];
#pragma unroll
      for (int n = 0; n < 4; ++n)
        bv[n] = *(const bfrag*)&sB[(wc + n * 16 + lr) * 64 + ks * 32 + lk];
#pragma unroll
      for (int m = 0; m < 4; ++m)
#pragma unroll
        for (int n = 0; n < 4; ++n)
          acc[m][n] = __builtin_amdgcn_mfma_f32_16x16x32_bf16(av[m], bv[n], acc[m][n], 0, 0, 0);
    }
    __syncthreads();
  }

  const int orow = (lane >> 4) * 4;
#pragma unroll
  for (int m = 0; m < 4; ++m) {
#pragma unroll
    for (int n = 0; n < 4; ++n) {
      const int r0 = m0 + wr + m * 16 + orow;        // global s-row base (mult of 4)
      const int c = n0 + wc + n * 16 + lr;            // global d-col
      const float bz = bias[c];
      const int bb = r0 >> 10, s = r0 & 1023;
      const int h = c >> 6, d = c & 63;
      uint2 v;
      v.x = pack2(acc[m][n][0] + bz, acc[m][n][1] + bz);
      v.y = pack2(acc[m][n][2] + bz, acc[m][n][3] + bz);
      *(uint2*)&Vt[(((size_t)bb * 16 + h) * 64 + d) * 1024 + s] = v;
    }
  }
}

// ---------------- attention ----------------
// block = (b, h, 64-row q-tile); 4 waves, wave w owns q-rows [w*16, w*16+16).
// Swapped QK^T: S^T = mfma(K, Q) so each lane owns a k-slice of ONE q-row.
// All LDS tiles XOR-swizzled: byte ^= ((row&7)<<4); staging pre-swizzles the
// global source so global_load_lds (linear dest) lands data swizzled.

__global__ __launch_bounds__(256) void attn_fwd(
    const u16* __restrict__ Qm, const u16* __restrict__ Km,
    const u16* __restrict__ Vt, const u16* __restrict__ posb,
    const u32* __restrict__ mbits, u16* __restrict__ Om) {
  const int b = blockIdx.x >> 4;
  const int qt = blockIdx.x & 15;
  const int h = blockIdx.y;
  const int t = threadIdx.x;
  const int w = t >> 6, lane = t & 63;
  const int lr = lane & 15, lg = lane >> 4;

  __shared__ u16 sQ[64 * 64];
  __shared__ u16 sK[64 * 64];
  __shared__ u16 sV[64 * 64];        // V^T tile: [d][k], swizzled
  __shared__ u16 sP[4][16 * 64];     // per-wave P, swizzled

  const int q0 = qt * 64;
  const size_t baseQ = ((size_t)b * 1024) * 1024 + (size_t)h * 64;
  const size_t baseV = ((size_t)(b * 16 + h) * 64) * 1024;

  // stage Q (swizzled via source permutation)
#pragma unroll
  for (int i = 0; i < 2; ++i) {
    const int idx = i * 256 + t;
    const int r = idx >> 3;
    const int w0 = (idx & 7) ^ (r & 7);
    gload_lds16(Qm + baseQ + (size_t)(q0 + r) * 1024 + w0 * 8, (char*)sQ + idx * 16);
  }
  __syncthreads();

  // hoist Q fragments (B-operand: q-row = w*16+lr, 8 contiguous dk per ks)
  bfrag qv[2];
#pragma unroll
  for (int ks = 0; ks < 2; ++ks) {
    const int byt = (w * 16 + lr) * 128 + ((ks * 64 + lg * 16) ^ ((lr & 7) << 4));
    qv[ks] = *(const bfrag*)((const char*)sQ + byt);
  }

  f32x4 o[4] = {};
  float m_q = -3.0e38f, l_q = 0.f;   // stats for q = q0 + w*16 + lr
  const int qg = q0 + w * 16 + lr;

  for (int kt = 0; kt < 16; ++kt) {
    const int k0 = kt * 64;
    __syncthreads();
#pragma unroll
    for (int i = 0; i < 2; ++i) {
      const int idx = i * 256 + t;
      const int r = idx >> 3;
      const int w0 = (idx & 7) ^ (r & 7);
      gload_lds16(Km + baseQ + (size_t)(k0 + r) * 1024 + w0 * 8, (char*)sK + idx * 16);
      gload_lds16(Vt + baseV + (size_t)r * 1024 + k0 + w0 * 8, (char*)sV + idx * 16);
    }
    __syncthreads();

    // S^T[k][q]: A = K rows, B = Q. Lane: k = k0 + n*16 + lg*4 + j, q = qg.
    f32x4 s[4] = {};
#pragma unroll
    for (int ks = 0; ks < 2; ++ks) {
#pragma unroll
      for (int n = 0; n < 4; ++n) {
        const int byt = (n * 16 + lr) * 128 + ((ks * 64 + lg * 16) ^ ((lr & 7) << 4));
        const bfrag kf = *(const bfrag*)((const char*)sK + byt);
        s[n] = __builtin_amdgcn_mfma_f32_16x16x32_bf16(kf, qv[ks], s[n], 0, 0, 0);
      }
    }

    // pos + mask (vectorized: 4x8B pos, 2x4B mask per lane)
    const u32 mw0 = mbits[((size_t)b * 1024 + qg) * 32 + (k0 >> 5)];
    const u32 mw1 = mbits[((size_t)b * 1024 + qg) * 32 + (k0 >> 5) + 1];
    float pv[16];
    float tmax = -3.0e38f;
#pragma unroll
    for (int n = 0; n < 4; ++n) {
      const uint2 pz = *(const uint2*)&posb[((size_t)h * 1024 + qg) * 1024 + k0 + n * 16 + lg * 4];
      const float pe[4] = {bf2f((u16)(pz.x & 0xffff)), bf2f((u16)(pz.x >> 16)),
                           bf2f((u16)(pz.y & 0xffff)), bf2f((u16)(pz.y >> 16))};
#pragma unroll
      for (int j = 0; j < 4; ++j) {
        const int kl = n * 16 + lg * 4 + j;
        float sv = s[n][j] + pe[j];
        const u32 mw = (kl & 32) ? mw1 : mw0;
        if (!((mw >> (kl & 31)) & 1u)) sv = -1.0e9f;
        pv[n * 4 + j] = sv;
        tmax = fmaxf(tmax, sv);
      }
    }

    // online softmax: in-lane 16 + 2 shfls (stats end up replicated per lr)
    tmax = fmaxf(tmax, __shfl_xor(tmax, 16));
    tmax = fmaxf(tmax, __shfl_xor(tmax, 32));
    const float mn = fmaxf(m_q, tmax);
    const float sc = __expf(m_q - mn);
    float rs = 0.f;
#pragma unroll
    for (int i = 0; i < 16; ++i) { pv[i] = __expf(pv[i] - mn); rs += pv[i]; }
    rs += __shfl_xor(rs, 16);
    rs += __shfl_xor(rs, 32);
    l_q = l_q * sc + rs;
    m_q = mn;

    // rescale O (o[n][j] belongs to q = q0 + w*16 + lg*4 + j)
#pragma unroll
    for (int j = 0; j < 4; ++j) {
      const float scj = __shfl(sc, lg * 4 + j);
#pragma unroll
      for (int n = 0; n < 4; ++n) o[n][j] *= scj;
    }

    // P -> per-wave swizzled LDS (4x ds_write_b64), read back as A-fragment
    char* pbuf = (char*)sP[w];
#pragma unroll
    for (int n = 0; n < 4; ++n) {
      uint2 pk;
      pk.x = pack2(pv[n * 4 + 0], pv[n * 4 + 1]);
      pk.y = pack2(pv[n * 4 + 2], pv[n * 4 + 3]);
      const int byt = lr * 128 + ((n * 32 + lg * 8) ^ ((lr & 7) << 4));
      *(uint2*)(pbuf + byt) = pk;
    }
#pragma unroll
    for (int ks = 0; ks < 2; ++ks) {
      const int pbyt = lr * 128 + ((ks * 64 + lg * 16) ^ ((lr & 7) << 4));
      const bfrag pf = *(const bfrag*)(pbuf + pbyt);
#pragma unroll
      for (int n = 0; n < 4; ++n) {
        const int vb = (n * 16 + lr) * 128 + ((ks * 64 + lg * 16) ^ ((lr & 7) << 4));
        const bfrag vf = *(const bfrag*)((const char*)sV + vb);
        o[n] = __builtin_amdgcn_mfma_f32_16x16x32_bf16(pf, vf, o[n], 0, 0, 0);
      }
    }
  }

  // normalize + write x_attn[b, q, h*64 + d]
#pragma unroll
  for (int j = 0; j < 4; ++j) {
    const float lj = __shfl(l_q, lg * 4 + j);
    const float inv = 1.f / lj;
    const int qr = q0 + w * 16 + lg * 4 + j;
#pragma unroll
    for (int n = 0; n < 4; ++n)
      Om[baseQ + (size_t)qr * 1024 + n * 16 + lr] = f2bf(o[n][j] * inv);
  }
}

// ---------------- launch ----------------

extern "C" void kernel_launch(void* const* d_in, const int* in_sizes, int n_in,
                              void* d_out, int out_size, void* d_ws, size_t ws_size,
                              hipStream_t stream) {
  const float* query = (const float*)d_in[0];
  const float* key_  = (const float*)d_in[1];
  const float* value = (const float*)d_in[2];
  const int*   mask  = (const int*)d_in[3];
  const float* pos   = (const float*)d_in[4];
  const float* wq = (const float*)d_in[5];
  const float* bq = (const float*)d_in[6];
  const float* wk = (const float*)d_in[7];
  const float* bk = (const float*)d_in[8];
  const float* wv = (const float*)d_in[9];
  const float* bv = (const float*)d_in[10];
  const float* wo = (const float*)d_in[11];
  const float* bo = (const float*)d_in[12];

  char* ws = (char*)d_ws;
  const size_t MB = 1024 * 1024;
  u16* wqb  = (u16*)(ws + 0 * MB);
  u16* wkb  = (u16*)(ws + 2 * MB);
  u16* wvb  = (u16*)(ws + 4 * MB);
  u16* wob  = (u16*)(ws + 6 * MB);
  u16* posb = (u16*)(ws + 8 * MB);     // 32MB  [H,S,S] bf16
  u16* Qb   = (u16*)(ws + 40 * MB);    // 16MB
  u16* Kb   = (u16*)(ws + 56 * MB);
  u16* Vtb  = (u16*)(ws + 72 * MB);    // 16MB  [B,H,64,S] bf16 (V transposed)
  u16* Xa   = (u16*)(ws + 88 * MB);
  u32* mb   = (u32*)(ws + 104 * MB);   // 1MB bitmask
  u16* wotb = (u16*)(ws + 105 * MB);   // 2MB  Wo^T bf16
  u16* W2b  = (u16*)(ws + 107 * MB);   // 2MB  (Wo@Wo) bf16
  float* bo2 = (float*)(ws + 109 * MB);            // 4KB
  float* zb  = (float*)(ws + 109 * MB + 4096);     // 4KB zero bias

  const float scl = 0.0883883476483184f;  // 1/sqrt(2*dk) = 1/sqrt(128)

  cast_v4<<<1024, 256, 0, stream>>>(wq, wqb, 262144);
  cast_v4<<<1024, 256, 0, stream>>>(wk, wkb, 262144);
  cast_v4<<<1024, 256, 0, stream>>>(wv, wvb, 262144);
  cast_v4<<<1024, 256, 0, stream>>>(wo, wob, 262144);
  cast_v4<<<16384, 256, 0, stream>>>(pos, posb, 4194304);
  pack_mask<<<1024, 256, 0, stream>>>(mask, mb);
  transpose_cast<<<dim3(16, 16), 256, 0, stream>>>(wo, wotb);
  bias2<<<256, 256, 0, stream>>>(wo, bo, bo2);
  hipMemsetAsync(zb, 0, 4096, stream);

  // W2 = Wo @ Wo  (A = Wo bf16, W-input = Wo^T in [N][K] layout)
  gemm_bt_a16<u16><<<dim3(8, 8), 256, 0, stream>>>(wob, wotb, zb, W2b, 1024, 1024, 1024);

  const dim3 gg(64, 8);
  gemm_bt_a32<u16><<<gg, 256, 0, stream>>>(query, wqb, bq, Qb, 8192, 1024, 1024, scl);
  gemm_bt_a32<u16><<<gg, 256, 0, stream>>>(key_,  wkb, bk, Kb, 8192, 1024, 1024, 1.0f);
  gemm_bt_a32_vt<<<gg, 256, 0, stream>>>(value, wvb, bv, Vtb, 8192, 1024, 1024);

  attn_fwd<<<dim3(128, 16), 256, 0, stream>>>(Qb, Kb, Vtb, posb, mb, Xa);

  // out = Xa @ W2^T + bo2   (folds the doubled output linear)
  gemm_bt_a16<float><<<gg, 256, 0, stream>>>(Xa, W2b, bo2, (float*)d_out, 8192, 1024, 1024);
}

// Round 3
// 321.015 us; speedup vs baseline: 1.3212x; 1.0745x over previous
//
#include <hip/hip_runtime.h>
#include <hip/hip_bf16.h>

typedef unsigned short u16;
typedef unsigned int u32;
typedef __attribute__((ext_vector_type(8))) short bfrag;   // 8 bf16 (4 VGPRs)
typedef __attribute__((ext_vector_type(4))) float f32x4;

#define DEVINL __device__ __forceinline__

DEVINL u16 f2bf(float f) {
  u32 u = __float_as_uint(f);
  u32 r = (u + 0x7fffu + ((u >> 16) & 1u)) >> 16;   // RNE
  return (u16)r;
}
DEVINL float bf2f(u16 u) { return __uint_as_float(((u32)u) << 16); }
// HW packed f32->bf16 (RNE), 1 inst for 2 elements
DEVINL u32 cvtpk(float lo, float hi) {
  u32 r;
  asm("v_cvt_pk_bf16_f32 %0, %1, %2" : "=v"(r) : "v"(lo), "v"(hi));
  return r;
}

DEVINL void gload_lds16(const void* g, void* l) {
  __builtin_amdgcn_global_load_lds(
      (const __attribute__((address_space(1))) void*)g,
      (__attribute__((address_space(3))) void*)l, 16, 0, 0);
}

DEVINL void storeC(u16* C, size_t idx, float v) { C[idx] = f2bf(v); }
DEVINL void storeC(float* C, size_t idx, float v) { C[idx] = v; }

// ---------------- prep kernels ----------------

__global__ void cast_v4(const float* __restrict__ in, u16* __restrict__ out, int n4, float s) {
  const int i = blockIdx.x * 256 + threadIdx.x;
  if (i < n4) {
    const float4 f = ((const float4*)in)[i];
    uint2 r;
    r.x = cvtpk(f.x * s, f.y * s);
    r.y = cvtpk(f.z * s, f.w * s);
    ((uint2*)out)[i] = r;
  }
}

__global__ void pack_mask(const int* __restrict__ mask, u32* __restrict__ bits) {
  const size_t wi = (size_t)blockIdx.x * 256 + threadIdx.x;
  const int* src = mask + wi * 32;
  u32 v = 0;
#pragma unroll
  for (int i = 0; i < 8; ++i) {
    const int4 m4 = ((const int4*)src)[i];
    if (m4.x) v |= 1u << (i * 4 + 0);
    if (m4.y) v |= 1u << (i * 4 + 1);
    if (m4.z) v |= 1u << (i * 4 + 2);
    if (m4.w) v |= 1u << (i * 4 + 3);
  }
  bits[wi] = v;
}

// transpose-cast: out[j][k] = bf16(in[k][j]), 1024x1024, grid(16,16), 256 thr
__global__ void transpose_cast(const float* __restrict__ in, u16* __restrict__ out) {
  __shared__ u16 tile[64][65];
  const int t = threadIdx.x;
  const int bx = blockIdx.x, by = blockIdx.y;
#pragma unroll
  for (int p = 0; p < 4; ++p) {
    const int r = (t >> 4) + p * 16;
    const int c = (t & 15) * 4;
    const float4 f = *(const float4*)&in[(size_t)(by * 64 + r) * 1024 + bx * 64 + c];
    tile[c + 0][r] = f2bf(f.x);
    tile[c + 1][r] = f2bf(f.y);
    tile[c + 2][r] = f2bf(f.z);
    tile[c + 3][r] = f2bf(f.w);
  }
  __syncthreads();
#pragma unroll
  for (int p = 0; p < 4; ++p) {
    const int r = (t >> 4) + p * 16;
    const int c = (t & 15) * 4;
    uint2 v;
    v.x = (u32)tile[r][c] | ((u32)tile[r][c + 1] << 16);
    v.y = (u32)tile[r][c + 2] | ((u32)tile[r][c + 3] << 16);
    *(uint2*)&out[(size_t)(bx * 64 + r) * 1024 + by * 64 + c] = v;
  }
}

// bo2 = Wo @ bo + bo ; one wave per output row
__global__ void bias2(const float* __restrict__ wo, const float* __restrict__ bo,
                      float* __restrict__ bo2) {
  const int w = threadIdx.x >> 6, lane = threadIdx.x & 63;
  const int row = blockIdx.x * 4 + w;
  const float* src = wo + (size_t)row * 1024;
  float s = 0.f;
#pragma unroll
  for (int i = 0; i < 4; ++i) {
    const float4 f = *(const float4*)&src[lane * 4 + i * 256];
    const float4 g = *(const float4*)&bo[lane * 4 + i * 256];
    s += f.x * g.x + f.y * g.y + f.z * g.z + f.w * g.w;
  }
#pragma unroll
  for (int d = 1; d < 64; d <<= 1) s += __shfl_xor(s, d);
  if (lane == 0) bo2[row] = s + bo[row];
}

// ---------------- GEMM: C[M,N] = (A[M,K] @ W[N,K]^T + bias) * oscale ----------------
// 128x128 tile, BK=64, 4 waves (2x2), each wave 64x64 = 4x4 frags of 16x16x32.

template <typename OutT>
__global__ __launch_bounds__(256) void gemm_bt_a16(
    const u16* __restrict__ A, const u16* __restrict__ W,
    const float* __restrict__ bias, OutT* __restrict__ C,
    int M, int N, int K) {
  __shared__ u16 sA[128 * 64];
  __shared__ u16 sB[128 * 64];
  const int t = threadIdx.x;
  const int w = t >> 6, lane = t & 63;
  const int lr = lane & 15, lk = (lane >> 4) * 8;
  const int m0 = blockIdx.x * 128, n0 = blockIdx.y * 128;
  const int wr = (w >> 1) * 64, wc = (w & 1) * 64;
  f32x4 acc[4][4] = {};

  for (int k0 = 0; k0 < K; k0 += 64) {
#pragma unroll
    for (int i = 0; i < 4; ++i) {
      const int idx = i * 256 + t;
      const int row = idx >> 3;
      const int col = (idx & 7) * 8;
      gload_lds16(A + (size_t)(m0 + row) * K + k0 + col, &sA[idx * 8]);
      gload_lds16(W + (size_t)(n0 + row) * K + k0 + col, &sB[idx * 8]);
    }
    __syncthreads();
#pragma unroll
    for (int ks = 0; ks < 2; ++ks) {
      bfrag av[4], bv[4];
#pragma unroll
      for (int m = 0; m < 4; ++m)
        av[m] = *(const bfrag*)&sA[(wr + m * 16 + lr) * 64 + ks * 32 + lk];
#pragma unroll
      for (int n = 0; n < 4; ++n)
        bv[n] = *(const bfrag*)&sB[(wc + n * 16 + lr) * 64 + ks * 32 + lk];
#pragma unroll
      for (int m = 0; m < 4; ++m)
#pragma unroll
        for (int n = 0; n < 4; ++n)
          acc[m][n] = __builtin_amdgcn_mfma_f32_16x16x32_bf16(av[m], bv[n], acc[m][n], 0, 0, 0);
    }
    __syncthreads();
  }

  const int orow = (lane >> 4) * 4;
#pragma unroll
  for (int m = 0; m < 4; ++m) {
#pragma unroll
    for (int n = 0; n < 4; ++n) {
      const int r = m0 + wr + m * 16 + orow;
      const int c = n0 + wc + n * 16 + lr;
      const float bz = bias[c];
#pragma unroll
      for (int j = 0; j < 4; ++j)
        storeC(C, (size_t)(r + j) * N + c, acc[m][n][j] + bz);
    }
  }
}

// A fp32 (cast to bf16 on stage via v_cvt_pk); optional output scale
template <typename OutT>
__global__ __launch_bounds__(256) void gemm_bt_a32(
    const float* __restrict__ A, const u16* __restrict__ W,
    const float* __restrict__ bias, OutT* __restrict__ C,
    int M, int N, int K, float oscale) {
  __shared__ u16 sA[128 * 64];
  __shared__ u16 sB[128 * 64];
  const int t = threadIdx.x;
  const int w = t >> 6, lane = t & 63;
  const int lr = lane & 15, lk = (lane >> 4) * 8;
  const int m0 = blockIdx.x * 128, n0 = blockIdx.y * 128;
  const int wr = (w >> 1) * 64, wc = (w & 1) * 64;
  f32x4 acc[4][4] = {};

  for (int k0 = 0; k0 < K; k0 += 64) {
#pragma unroll
    for (int i = 0; i < 4; ++i) {
      const int idx = i * 256 + t;
      const int row = idx >> 3;
      const int col = (idx & 7) * 8;
      const float* src = A + (size_t)(m0 + row) * K + k0 + col;
      const float4 f0 = *(const float4*)src;
      const float4 f1 = *(const float4*)(src + 4);
      uint4 pk;
      pk.x = cvtpk(f0.x, f0.y);
      pk.y = cvtpk(f0.z, f0.w);
      pk.z = cvtpk(f1.x, f1.y);
      pk.w = cvtpk(f1.z, f1.w);
      *(uint4*)&sA[idx * 8] = pk;   // one ds_write_b128
      gload_lds16(W + (size_t)(n0 + row) * K + k0 + col, &sB[idx * 8]);
    }
    __syncthreads();
#pragma unroll
    for (int ks = 0; ks < 2; ++ks) {
      bfrag av[4], bv[4];
#pragma unroll
      for (int m = 0; m < 4; ++m)
        av[m] = *(const bfrag*)&sA[(wr + m * 16 + lr) * 64 + ks * 32 + lk];
#pragma unroll
      for (int n = 0; n < 4; ++n)
        bv[n] = *(const bfrag*)&sB[(wc + n * 16 + lr) * 64 + ks * 32 + lk];
#pragma unroll
      for (int m = 0; m < 4; ++m)
#pragma unroll
        for (int n = 0; n < 4; ++n)
          acc[m][n] = __builtin_amdgcn_mfma_f32_16x16x32_bf16(av[m], bv[n], acc[m][n], 0, 0, 0);
    }
    __syncthreads();
  }

  const int orow = (lane >> 4) * 4;
#pragma unroll
  for (int m = 0; m < 4; ++m) {
#pragma unroll
    for (int n = 0; n < 4; ++n) {
      const int r = m0 + wr + m * 16 + orow;
      const int c = n0 + wc + n * 16 + lr;
      const float bz = bias[c];
#pragma unroll
      for (int j = 0; j < 4; ++j)
        storeC(C, (size_t)(r + j) * N + c, (acc[m][n][j] + bz) * oscale);
    }
  }
}

// V projection writing transposed output Vt[((b*16+h)*64 + d)*1024 + s]
__global__ __launch_bounds__(256) void gemm_bt_a32_vt(
    const float* __restrict__ A, const u16* __restrict__ W,
    const float* __restrict__ bias, u16* __restrict__ Vt,
    int M, int N, int K) {
  __shared__ u16 sA[128 * 64];
  __shared__ u16 sB[128 * 64];
  const int t = threadIdx.x;
  const int w = t >> 6, lane = t & 63;
  const int lr = lane & 15, lk = (lane >> 4) * 8;
  const int m0 = blockIdx.x * 128, n0 = blockIdx.y * 128;
  const int wr = (w >> 1) * 64, wc = (w & 1) * 64;
  f32x4 acc[4][4] = {};

  for (int k0 = 0; k0 < K; k0 += 64) {
#pragma unroll
    for (int i = 0; i < 4; ++i) {
      const int idx = i * 256 + t;
      const int row = idx >> 3;
      const int col = (idx & 7) * 8;
      const float* src = A + (size_t)(m0 + row) * K + k0 + col;
      const float4 f0 = *(const float4*)src;
      const float4 f1 = *(const float4*)(src + 4);
      uint4 pk;
      pk.x = cvtpk(f0.x, f0.y);
      pk.y = cvtpk(f0.z, f0.w);
      pk.z = cvtpk(f1.x, f1.y);
      pk.w = cvtpk(f1.z, f1.w);
      *(uint4*)&sA[idx * 8] = pk;
      gload_lds16(W + (size_t)(n0 + row) * K + k0 + col, &sB[idx * 8]);
    }
    __syncthreads();
#pragma unroll
    for (int ks = 0; ks < 2; ++ks) {
      bfrag av[4], bv[4];
#pragma unroll
      for (int m = 0; m < 4; ++m)
        av[m] = *(const bfrag*)&sA[(wr + m * 16 + lr) * 64 + ks * 32 + lk];
#pragma unroll
      for (int n = 0; n < 4; ++n)
        bv[n] = *(const bfrag*)&sB[(wc + n * 16 + lr) * 64 + ks * 32 + lk];
#pragma unroll
      for (int m = 0; m < 4; ++m)
#pragma unroll
        for (int n = 0; n < 4; ++n)
          acc[m][n] = __builtin_amdgcn_mfma_f32_16x16x32_bf16(av[m], bv[n], acc[m][n], 0, 0, 0);
    }
    __syncthreads();
  }

  const int orow = (lane >> 4) * 4;
#pragma unroll
  for (int m = 0; m < 4; ++m) {
#pragma unroll
    for (int n = 0; n < 4; ++n) {
      const int r0 = m0 + wr + m * 16 + orow;        // global s-row base (mult of 4)
      const int c = n0 + wc + n * 16 + lr;            // global d-col
      const float bz = bias[c];
      const int bb = r0 >> 10, s = r0 & 1023;
      const int h = c >> 6, d = c & 63;
      uint2 v;
      v.x = cvtpk(acc[m][n][0] + bz, acc[m][n][1] + bz);
      v.y = cvtpk(acc[m][n][2] + bz, acc[m][n][3] + bz);
      *(uint2*)&Vt[(((size_t)bb * 16 + h) * 64 + d) * 1024 + s] = v;
    }
  }
}

// ---------------- attention ----------------
// block = (b, h, 64-row q-tile); 4 waves. Swapped QK^T (lane owns one q-row's
// k-slice). Double-buffered K/V prefetch (T3 2-phase); sQ region reused as
// V-buffer-1 after Q-fragment hoist. exp2-domain softmax (log2e folded into
// Q-scale and pos). Defer-max rescale (T13, THR=8). All LDS tiles XOR-swizzled.

__global__ __launch_bounds__(256) void attn_fwd(
    const u16* __restrict__ Qm, const u16* __restrict__ Km,
    const u16* __restrict__ Vt, const u16* __restrict__ posb,
    const u32* __restrict__ mbits, u16* __restrict__ Om) {
  const int bb = blockIdx.x >> 4;
  const int qt = blockIdx.x & 15;
  const int h = blockIdx.y;
  const int t = threadIdx.x;
  const int w = t >> 6, lane = t & 63;
  const int lr = lane & 15, lg = lane >> 4;

  // 0..8K: sQ then sV1 | 8..16K: sK0 | 16..24K: sK1 | 24..32K: sV0 | 32..40K: sP
  __shared__ __align__(16) char smem[40960];

  const int q0 = qt * 64;
  const size_t baseQ = ((size_t)bb * 1024) * 1024 + (size_t)h * 64;
  const size_t baseV = ((size_t)(bb * 16 + h) * 64) * 1024;
  const int qg = q0 + w * 16 + lr;
  const u16* posrow = posb + ((size_t)h * 1024 + qg) * 1024;
  const u32* mrow = mbits + ((size_t)bb * 1024 + qg) * 32;

  // stage Q (swizzled via source permutation)
#pragma unroll
  for (int i = 0; i < 2; ++i) {
    const int idx = i * 256 + t;
    const int r = idx >> 3;
    const int w0 = (idx & 7) ^ (r & 7);
    gload_lds16(Qm + baseQ + (size_t)(q0 + r) * 1024 + w0 * 8, smem + idx * 16);
  }
  __syncthreads();

  // hoist Q fragments (B-operand)
  bfrag qv[2];
#pragma unroll
  for (int ks = 0; ks < 2; ++ks) {
    const int byt = (w * 16 + lr) * 128 + ((ks * 64 + lg * 16) ^ ((lr & 7) << 4));
    qv[ks] = *(const bfrag*)(smem + byt);
  }

  // prologue: stage kt=0 into buf0, prefetch pos/mask for kt=0
#pragma unroll
  for (int i = 0; i < 2; ++i) {
    const int idx = i * 256 + t;
    const int r = idx >> 3;
    const int w0 = (idx & 7) ^ (r & 7);
    gload_lds16(Km + baseQ + (size_t)r * 1024 + w0 * 8, smem + 8192 + idx * 16);
    gload_lds16(Vt + baseV + (size_t)r * 1024 + w0 * 8, smem + 24576 + idx * 16);
  }
  uint2 pz[4];
  u32 mk0, mk1;
#pragma unroll
  for (int n = 0; n < 4; ++n) pz[n] = *(const uint2*)&posrow[n * 16 + lg * 4];
  mk0 = mrow[0];
  mk1 = mrow[1];
  __syncthreads();  // Q hoisted by all waves; buf0 loads landed

  f32x4 o[4] = {};
  float m_q = -3.0e38f, l_q = 0.f;

  for (int kt = 0; kt < 16; ++kt) {
    const int cur = kt & 1;
    const char* sK = smem + 8192 + cur * 8192;
    const char* sV = cur ? smem : (smem + 24576);

    uint2 pzn[4];
    u32 mkn0 = 0, mkn1 = 0;
    if (kt < 15) {
      const int kn = (kt + 1) * 64;
      const int nb = cur ^ 1;
      char* dK = smem + 8192 + nb * 8192;
      char* dV = nb ? smem : (smem + 24576);
#pragma unroll
      for (int i = 0; i < 2; ++i) {
        const int idx = i * 256 + t;
        const int r = idx >> 3;
        const int w0 = (idx & 7) ^ (r & 7);
        gload_lds16(Km + baseQ + (size_t)(kn + r) * 1024 + w0 * 8, dK + idx * 16);
        gload_lds16(Vt + baseV + (size_t)r * 1024 + kn + w0 * 8, dV + idx * 16);
      }
#pragma unroll
      for (int n = 0; n < 4; ++n) pzn[n] = *(const uint2*)&posrow[kn + n * 16 + lg * 4];
      mkn0 = mrow[(kn >> 5)];
      mkn1 = mrow[(kn >> 5) + 1];
    }

    // S^T[k][q] = mfma(K, Q); lane: k = n*16 + lg*4 + j (local), q = qg
    f32x4 s[4] = {};
#pragma unroll
    for (int ks = 0; ks < 2; ++ks) {
#pragma unroll
      for (int n = 0; n < 4; ++n) {
        const int byt = (n * 16 + lr) * 128 + ((ks * 64 + lg * 16) ^ ((lr & 7) << 4));
        const bfrag kf = *(const bfrag*)(sK + byt);
        s[n] = __builtin_amdgcn_mfma_f32_16x16x32_bf16(kf, qv[ks], s[n], 0, 0, 0);
      }
    }

    // pos + mask (exp2 domain; pos pre-scaled by log2e, Q by scl*log2e)
    float pv[16];
    float tmax = -3.0e38f;
#pragma unroll
    for (int n = 0; n < 4; ++n) {
      const float pe[4] = {bf2f((u16)(pz[n].x & 0xffff)), bf2f((u16)(pz[n].x >> 16)),
                           bf2f((u16)(pz[n].y & 0xffff)), bf2f((u16)(pz[n].y >> 16))};
#pragma unroll
      for (int j = 0; j < 4; ++j) {
        const int kl = n * 16 + lg * 4 + j;
        float sv = s[n][j] + pe[j];
        const u32 mw = (kl & 32) ? mk1 : mk0;
        if (!((mw >> (kl & 31)) & 1u)) sv = -1.0e9f;
        pv[n * 4 + j] = sv;
        tmax = fmaxf(tmax, sv);
      }
    }

    // online softmax stats (replicated across the 4 lanes sharing lr)
    tmax = fmaxf(tmax, __shfl_xor(tmax, 16));
    tmax = fmaxf(tmax, __shfl_xor(tmax, 32));
    if (!__all(tmax <= m_q + 8.0f)) {       // defer-max: skip rescale when growth small
      const float mn = fmaxf(m_q, tmax);
      const float sc = __builtin_amdgcn_exp2f(m_q - mn);
      l_q *= sc;
#pragma unroll
      for (int j = 0; j < 4; ++j) {
        const float scj = __shfl(sc, lg * 4 + j);
#pragma unroll
        for (int n = 0; n < 4; ++n) o[n][j] *= scj;
      }
      m_q = mn;
    }
    float rs = 0.f;
#pragma unroll
    for (int i2 = 0; i2 < 16; ++i2) {
      pv[i2] = __builtin_amdgcn_exp2f(pv[i2] - m_q);
      rs += pv[i2];
    }
    rs += __shfl_xor(rs, 16);
    rs += __shfl_xor(rs, 32);
    l_q += rs;

    // P -> per-wave swizzled LDS (packed via v_cvt_pk), read back as A-fragment
    char* pbuf = smem + 32768 + w * 2048;
#pragma unroll
    for (int n = 0; n < 4; ++n) {
      uint2 pk;
      pk.x = cvtpk(pv[n * 4 + 0], pv[n * 4 + 1]);
      pk.y = cvtpk(pv[n * 4 + 2], pv[n * 4 + 3]);
      const int byt = lr * 128 + ((n * 32 + lg * 8) ^ ((lr & 7) << 4));
      *(uint2*)(pbuf + byt) = pk;
    }
#pragma unroll
    for (int ks = 0; ks < 2; ++ks) {
      const int pbyt = lr * 128 + ((ks * 64 + lg * 16) ^ ((lr & 7) << 4));
      const bfrag pf = *(const bfrag*)(pbuf + pbyt);
#pragma unroll
      for (int n = 0; n < 4; ++n) {
        const int vb = (n * 16 + lr) * 128 + ((ks * 64 + lg * 16) ^ ((lr & 7) << 4));
        const bfrag vf = *(const bfrag*)(sV + vb);
        o[n] = __builtin_amdgcn_mfma_f32_16x16x32_bf16(pf, vf, o[n], 0, 0, 0);
      }
    }

    __syncthreads();   // drains prefetch vmcnt; next buffers ready

    if (kt < 15) {
#pragma unroll
      for (int n = 0; n < 4; ++n) pz[n] = pzn[n];
      mk0 = mkn0;
      mk1 = mkn1;
    }
  }

  // normalize + write x_attn[b, q, h*64 + d]
#pragma unroll
  for (int j = 0; j < 4; ++j) {
    const float lj = __shfl(l_q, lg * 4 + j);
    const float inv = 1.f / lj;
    const int qr = q0 + w * 16 + lg * 4 + j;
#pragma unroll
    for (int n = 0; n < 4; ++n)
      Om[baseQ + (size_t)qr * 1024 + n * 16 + lr] = f2bf(o[n][j] * inv);
  }
}

// ---------------- launch ----------------

extern "C" void kernel_launch(void* const* d_in, const int* in_sizes, int n_in,
                              void* d_out, int out_size, void* d_ws, size_t ws_size,
                              hipStream_t stream) {
  const float* query = (const float*)d_in[0];
  const float* key_  = (const float*)d_in[1];
  const float* value = (const float*)d_in[2];
  const int*   mask  = (const int*)d_in[3];
  const float* pos   = (const float*)d_in[4];
  const float* wq = (const float*)d_in[5];
  const float* bq = (const float*)d_in[6];
  const float* wk = (const float*)d_in[7];
  const float* bk = (const float*)d_in[8];
  const float* wv = (const float*)d_in[9];
  const float* bv = (const float*)d_in[10];
  const float* wo = (const float*)d_in[11];
  const float* bo = (const float*)d_in[12];

  char* ws = (char*)d_ws;
  const size_t MB = 1024 * 1024;
  u16* wqb  = (u16*)(ws + 0 * MB);
  u16* wkb  = (u16*)(ws + 2 * MB);
  u16* wvb  = (u16*)(ws + 4 * MB);
  u16* wob  = (u16*)(ws + 6 * MB);
  u16* posb = (u16*)(ws + 8 * MB);     // 32MB  [H,S,S] bf16 (pre-scaled by log2e)
  u16* Qb   = (u16*)(ws + 40 * MB);    // 16MB
  u16* Kb   = (u16*)(ws + 56 * MB);
  u16* Vtb  = (u16*)(ws + 72 * MB);    // 16MB  [B,H,64,S] bf16 (V transposed)
  u16* Xa   = (u16*)(ws + 88 * MB);
  u32* mb   = (u32*)(ws + 104 * MB);   // 1MB bitmask
  u16* wotb = (u16*)(ws + 105 * MB);   // 2MB  Wo^T bf16
  u16* W2b  = (u16*)(ws + 107 * MB);   // 2MB  (Wo@Wo) bf16
  float* bo2 = (float*)(ws + 109 * MB);            // 4KB
  float* zb  = (float*)(ws + 109 * MB + 4096);     // 4KB zero bias

  const float log2e = 1.4426950408889634f;
  const float qs = 0.0883883476483184f * log2e;   // (1/sqrt(2*dk)) * log2e

  cast_v4<<<1024, 256, 0, stream>>>(wq, wqb, 262144, 1.0f);
  cast_v4<<<1024, 256, 0, stream>>>(wk, wkb, 262144, 1.0f);
  cast_v4<<<1024, 256, 0, stream>>>(wv, wvb, 262144, 1.0f);
  cast_v4<<<1024, 256, 0, stream>>>(wo, wob, 262144, 1.0f);
  cast_v4<<<16384, 256, 0, stream>>>(pos, posb, 4194304, log2e);
  pack_mask<<<1024, 256, 0, stream>>>(mask, mb);
  transpose_cast<<<dim3(16, 16), 256, 0, stream>>>(wo, wotb);
  bias2<<<256, 256, 0, stream>>>(wo, bo, bo2);
  hipMemsetAsync(zb, 0, 4096, stream);

  // W2 = Wo @ Wo  (A = Wo bf16, W-input = Wo^T in [N][K] layout)
  gemm_bt_a16<u16><<<dim3(8, 8), 256, 0, stream>>>(wob, wotb, zb, W2b, 1024, 1024, 1024);

  const dim3 gg(64, 8);
  gemm_bt_a32<u16><<<gg, 256, 0, stream>>>(query, wqb, bq, Qb, 8192, 1024, 1024, qs);
  gemm_bt_a32<u16><<<gg, 256, 0, stream>>>(key_,  wkb, bk, Kb, 8192, 1024, 1024, 1.0f);
  gemm_bt_a32_vt<<<gg, 256, 0, stream>>>(value, wvb, bv, Vtb, 8192, 1024, 1024);

  attn_fwd<<<dim3(128, 16), 256, 0, stream>>>(Qb, Kb, Vtb, posb, mb, Xa);

  // out = Xa @ W2^T + bo2   (folds the doubled output linear)
  gemm_bt_a16<float><<<gg, 256, 0, stream>>>(Xa, W2b, bo2, (float*)d_out, 8192, 1024, 1024);
}

// Round 4
// 286.664 us; speedup vs baseline: 1.4795x; 1.1198x over previous
//
#include <hip/hip_runtime.h>
#include <hip/hip_bf16.h>

typedef unsigned short u16;
typedef unsigned int u32;
typedef __attribute__((ext_vector_type(8))) short bfrag;   // 8 bf16 (4 VGPRs)
typedef __attribute__((ext_vector_type(4))) float f32x4;

#define DEVINL __device__ __forceinline__

DEVINL u16 f2bf(float f) {
  u32 u = __float_as_uint(f);
  u32 r = (u + 0x7fffu + ((u >> 16) & 1u)) >> 16;   // RNE
  return (u16)r;
}
DEVINL float bf2f(u16 u) { return __uint_as_float(((u32)u) << 16); }
// HW packed f32->bf16 (RNE), 1 inst for 2 elements
DEVINL u32 cvtpk(float lo, float hi) {
  u32 r;
  asm("v_cvt_pk_bf16_f32 %0, %1, %2" : "=v"(r) : "v"(lo), "v"(hi));
  return r;
}
DEVINL u16 f2bf_hw(float v) { return (u16)cvtpk(v, v); }
DEVINL float fmax3(float a, float b, float c) { return fmaxf(fmaxf(a, b), c); }  // fuses to v_max3_f32

DEVINL void gload_lds16(const void* g, void* l) {
  __builtin_amdgcn_global_load_lds(
      (const __attribute__((address_space(1))) void*)g,
      (__attribute__((address_space(3))) void*)l, 16, 0, 0);
}

DEVINL void storeC(u16* C, size_t idx, float v) { C[idx] = f2bf_hw(v); }
DEVINL void storeC(float* C, size_t idx, float v) { C[idx] = v; }

// ---------------- prep kernels ----------------

__global__ void cast_v4(const float* __restrict__ in, u16* __restrict__ out, int n4, float s) {
  const int i = blockIdx.x * 256 + threadIdx.x;
  if (i < n4) {
    const float4 f = ((const float4*)in)[i];
    uint2 r;
    r.x = cvtpk(f.x * s, f.y * s);
    r.y = cvtpk(f.z * s, f.w * s);
    ((uint2*)out)[i] = r;
  }
}

__global__ void pack_mask(const int* __restrict__ mask, u32* __restrict__ bits) {
  const size_t wi = (size_t)blockIdx.x * 256 + threadIdx.x;
  const int* src = mask + wi * 32;
  u32 v = 0;
#pragma unroll
  for (int i = 0; i < 8; ++i) {
    const int4 m4 = ((const int4*)src)[i];
    if (m4.x) v |= 1u << (i * 4 + 0);
    if (m4.y) v |= 1u << (i * 4 + 1);
    if (m4.z) v |= 1u << (i * 4 + 2);
    if (m4.w) v |= 1u << (i * 4 + 3);
  }
  bits[wi] = v;
}

// transpose-cast: out[j][k] = bf16(in[k][j]), 1024x1024, grid(16,16), 256 thr
__global__ void transpose_cast(const float* __restrict__ in, u16* __restrict__ out) {
  __shared__ u16 tile[64][65];
  const int t = threadIdx.x;
  const int bx = blockIdx.x, by = blockIdx.y;
#pragma unroll
  for (int p = 0; p < 4; ++p) {
    const int r = (t >> 4) + p * 16;
    const int c = (t & 15) * 4;
    const float4 f = *(const float4*)&in[(size_t)(by * 64 + r) * 1024 + bx * 64 + c];
    tile[c + 0][r] = f2bf(f.x);
    tile[c + 1][r] = f2bf(f.y);
    tile[c + 2][r] = f2bf(f.z);
    tile[c + 3][r] = f2bf(f.w);
  }
  __syncthreads();
#pragma unroll
  for (int p = 0; p < 4; ++p) {
    const int r = (t >> 4) + p * 16;
    const int c = (t & 15) * 4;
    uint2 v;
    v.x = (u32)tile[r][c] | ((u32)tile[r][c + 1] << 16);
    v.y = (u32)tile[r][c + 2] | ((u32)tile[r][c + 3] << 16);
    *(uint2*)&out[(size_t)(bx * 64 + r) * 1024 + by * 64 + c] = v;
  }
}

// bo2 = Wo @ bo + bo ; one wave per output row
__global__ void bias2(const float* __restrict__ wo, const float* __restrict__ bo,
                      float* __restrict__ bo2) {
  const int w = threadIdx.x >> 6, lane = threadIdx.x & 63;
  const int row = blockIdx.x * 4 + w;
  const float* src = wo + (size_t)row * 1024;
  float s = 0.f;
#pragma unroll
  for (int i = 0; i < 4; ++i) {
    const float4 f = *(const float4*)&src[lane * 4 + i * 256];
    const float4 g = *(const float4*)&bo[lane * 4 + i * 256];
    s += f.x * g.x + f.y * g.y + f.z * g.z + f.w * g.w;
  }
#pragma unroll
  for (int d = 1; d < 64; d <<= 1) s += __shfl_xor(s, d);
  if (lane == 0) bo2[row] = s + bo[row];
}

// small GEMM, 64x64 tile (for W2 = Wo@Wo): C = A @ W^T, no bias
__global__ __launch_bounds__(256) void gemm_bt_64(
    const u16* __restrict__ A, const u16* __restrict__ W,
    u16* __restrict__ C, int N, int K) {
  __shared__ u16 sA[64 * 64];
  __shared__ u16 sB[64 * 64];
  const int t = threadIdx.x;
  const int w = t >> 6, lane = t & 63;
  const int lr = lane & 15, lk = (lane >> 4) * 8;
  const int m0 = blockIdx.x * 64, n0 = blockIdx.y * 64;
  f32x4 acc[4] = {};
  for (int k0 = 0; k0 < K; k0 += 64) {
#pragma unroll
    for (int i = 0; i < 2; ++i) {
      const int idx = i * 256 + t;
      const int row = idx >> 3;
      const int col = (idx & 7) * 8;
      gload_lds16(A + (size_t)(m0 + row) * K + k0 + col, &sA[idx * 8]);
      gload_lds16(W + (size_t)(n0 + row) * K + k0 + col, &sB[idx * 8]);
    }
    __syncthreads();
#pragma unroll
    for (int ks = 0; ks < 2; ++ks) {
      const bfrag av = *(const bfrag*)&sA[(w * 16 + lr) * 64 + ks * 32 + lk];
#pragma unroll
      for (int n = 0; n < 4; ++n) {
        const bfrag bv = *(const bfrag*)&sB[(n * 16 + lr) * 64 + ks * 32 + lk];
        acc[n] = __builtin_amdgcn_mfma_f32_16x16x32_bf16(av, bv, acc[n], 0, 0, 0);
      }
    }
    __syncthreads();
  }
  const int orow = (lane >> 4) * 4;
#pragma unroll
  for (int n = 0; n < 4; ++n)
#pragma unroll
    for (int j = 0; j < 4; ++j)
      C[(size_t)(m0 + w * 16 + orow + j) * N + n0 + n * 16 + lr] = f2bf_hw(acc[n][j]);
}

// ---------------- GEMM: C[M,N] = (A[M,K] @ W[N,K]^T + bias) * oscale ----------------
// 128x128 tile, BK=64, 4 waves (2x2), each wave 64x64 = 4x4 frags of 16x16x32.

template <typename OutT>
__global__ __launch_bounds__(256) void gemm_bt_a16(
    const u16* __restrict__ A, const u16* __restrict__ W,
    const float* __restrict__ bias, OutT* __restrict__ C,
    int M, int N, int K) {
  __shared__ u16 sA[128 * 64];
  __shared__ u16 sB[128 * 64];
  const int t = threadIdx.x;
  const int w = t >> 6, lane = t & 63;
  const int lr = lane & 15, lk = (lane >> 4) * 8;
  const int m0 = blockIdx.x * 128, n0 = blockIdx.y * 128;
  const int wr = (w >> 1) * 64, wc = (w & 1) * 64;
  f32x4 acc[4][4] = {};

  for (int k0 = 0; k0 < K; k0 += 64) {
#pragma unroll
    for (int i = 0; i < 4; ++i) {
      const int idx = i * 256 + t;
      const int row = idx >> 3;
      const int col = (idx & 7) * 8;
      gload_lds16(A + (size_t)(m0 + row) * K + k0 + col, &sA[idx * 8]);
      gload_lds16(W + (size_t)(n0 + row) * K + k0 + col, &sB[idx * 8]);
    }
    __syncthreads();
#pragma unroll
    for (int ks = 0; ks < 2; ++ks) {
      bfrag av[4], bv[4];
#pragma unroll
      for (int m = 0; m < 4; ++m)
        av[m] = *(const bfrag*)&sA[(wr + m * 16 + lr) * 64 + ks * 32 + lk];
#pragma unroll
      for (int n = 0; n < 4; ++n)
        bv[n] = *(const bfrag*)&sB[(wc + n * 16 + lr) * 64 + ks * 32 + lk];
#pragma unroll
      for (int m = 0; m < 4; ++m)
#pragma unroll
        for (int n = 0; n < 4; ++n)
          acc[m][n] = __builtin_amdgcn_mfma_f32_16x16x32_bf16(av[m], bv[n], acc[m][n], 0, 0, 0);
    }
    __syncthreads();
  }

  const int orow = (lane >> 4) * 4;
#pragma unroll
  for (int m = 0; m < 4; ++m) {
#pragma unroll
    for (int n = 0; n < 4; ++n) {
      const int r = m0 + wr + m * 16 + orow;
      const int c = n0 + wc + n * 16 + lr;
      const float bz = bias[c];
#pragma unroll
      for (int j = 0; j < 4; ++j)
        storeC(C, (size_t)(r + j) * N + c, acc[m][n][j] + bz);
    }
  }
}

// A fp32 (cast to bf16 on stage via v_cvt_pk); optional output scale
template <typename OutT>
__global__ __launch_bounds__(256) void gemm_bt_a32(
    const float* __restrict__ A, const u16* __restrict__ W,
    const float* __restrict__ bias, OutT* __restrict__ C,
    int M, int N, int K, float oscale) {
  __shared__ u16 sA[128 * 64];
  __shared__ u16 sB[128 * 64];
  const int t = threadIdx.x;
  const int w = t >> 6, lane = t & 63;
  const int lr = lane & 15, lk = (lane >> 4) * 8;
  const int m0 = blockIdx.x * 128, n0 = blockIdx.y * 128;
  const int wr = (w >> 1) * 64, wc = (w & 1) * 64;
  f32x4 acc[4][4] = {};

  for (int k0 = 0; k0 < K; k0 += 64) {
#pragma unroll
    for (int i = 0; i < 4; ++i) {
      const int idx = i * 256 + t;
      const int row = idx >> 3;
      const int col = (idx & 7) * 8;
      const float* src = A + (size_t)(m0 + row) * K + k0 + col;
      const float4 f0 = *(const float4*)src;
      const float4 f1 = *(const float4*)(src + 4);
      uint4 pk;
      pk.x = cvtpk(f0.x, f0.y);
      pk.y = cvtpk(f0.z, f0.w);
      pk.z = cvtpk(f1.x, f1.y);
      pk.w = cvtpk(f1.z, f1.w);
      *(uint4*)&sA[idx * 8] = pk;   // one ds_write_b128
      gload_lds16(W + (size_t)(n0 + row) * K + k0 + col, &sB[idx * 8]);
    }
    __syncthreads();
#pragma unroll
    for (int ks = 0; ks < 2; ++ks) {
      bfrag av[4], bv[4];
#pragma unroll
      for (int m = 0; m < 4; ++m)
        av[m] = *(const bfrag*)&sA[(wr + m * 16 + lr) * 64 + ks * 32 + lk];
#pragma unroll
      for (int n = 0; n < 4; ++n)
        bv[n] = *(const bfrag*)&sB[(wc + n * 16 + lr) * 64 + ks * 32 + lk];
#pragma unroll
      for (int m = 0; m < 4; ++m)
#pragma unroll
        for (int n = 0; n < 4; ++n)
          acc[m][n] = __builtin_amdgcn_mfma_f32_16x16x32_bf16(av[m], bv[n], acc[m][n], 0, 0, 0);
    }
    __syncthreads();
  }

  const int orow = (lane >> 4) * 4;
#pragma unroll
  for (int m = 0; m < 4; ++m) {
#pragma unroll
    for (int n = 0; n < 4; ++n) {
      const int r = m0 + wr + m * 16 + orow;
      const int c = n0 + wc + n * 16 + lr;
      const float bz = bias[c];
#pragma unroll
      for (int j = 0; j < 4; ++j)
        storeC(C, (size_t)(r + j) * N + c, (acc[m][n][j] + bz) * oscale);
    }
  }
}

// V projection writing transposed output Vt[((b*16+h)*64 + d)*1024 + s]
__global__ __launch_bounds__(256) void gemm_bt_a32_vt(
    const float* __restrict__ A, const u16* __restrict__ W,
    const float* __restrict__ bias, u16* __restrict__ Vt,
    int M, int N, int K) {
  __shared__ u16 sA[128 * 64];
  __shared__ u16 sB[128 * 64];
  const int t = threadIdx.x;
  const int w = t >> 6, lane = t & 63;
  const int lr = lane & 15, lk = (lane >> 4) * 8;
  const int m0 = blockIdx.x * 128, n0 = blockIdx.y * 128;
  const int wr = (w >> 1) * 64, wc = (w & 1) * 64;
  f32x4 acc[4][4] = {};

  for (int k0 = 0; k0 < K; k0 += 64) {
#pragma unroll
    for (int i = 0; i < 4; ++i) {
      const int idx = i * 256 + t;
      const int row = idx >> 3;
      const int col = (idx & 7) * 8;
      const float* src = A + (size_t)(m0 + row) * K + k0 + col;
      const float4 f0 = *(const float4*)src;
      const float4 f1 = *(const float4*)(src + 4);
      uint4 pk;
      pk.x = cvtpk(f0.x, f0.y);
      pk.y = cvtpk(f0.z, f0.w);
      pk.z = cvtpk(f1.x, f1.y);
      pk.w = cvtpk(f1.z, f1.w);
      *(uint4*)&sA[idx * 8] = pk;
      gload_lds16(W + (size_t)(n0 + row) * K + k0 + col, &sB[idx * 8]);
    }
    __syncthreads();
#pragma unroll
    for (int ks = 0; ks < 2; ++ks) {
      bfrag av[4], bv[4];
#pragma unroll
      for (int m = 0; m < 4; ++m)
        av[m] = *(const bfrag*)&sA[(wr + m * 16 + lr) * 64 + ks * 32 + lk];
#pragma unroll
      for (int n = 0; n < 4; ++n)
        bv[n] = *(const bfrag*)&sB[(wc + n * 16 + lr) * 64 + ks * 32 + lk];
#pragma unroll
      for (int m = 0; m < 4; ++m)
#pragma unroll
        for (int n = 0; n < 4; ++n)
          acc[m][n] = __builtin_amdgcn_mfma_f32_16x16x32_bf16(av[m], bv[n], acc[m][n], 0, 0, 0);
    }
    __syncthreads();
  }

  const int orow = (lane >> 4) * 4;
#pragma unroll
  for (int m = 0; m < 4; ++m) {
#pragma unroll
    for (int n = 0; n < 4; ++n) {
      const int r0 = m0 + wr + m * 16 + orow;        // global s-row base (mult of 4)
      const int c = n0 + wc + n * 16 + lr;            // global d-col
      const float bz = bias[c];
      const int bb = r0 >> 10, s = r0 & 1023;
      const int h = c >> 6, d = c & 63;
      uint2 v;
      v.x = cvtpk(acc[m][n][0] + bz, acc[m][n][1] + bz);
      v.y = cvtpk(acc[m][n][2] + bz, acc[m][n][3] + bz);
      *(uint2*)&Vt[(((size_t)bb * 16 + h) * 64 + d) * 1024 + s] = v;
    }
  }
}

// ---------------- attention ----------------
// block = (b, h, 128-row q-tile); 8 waves, wave w owns q-rows [w*16,(w+1)*16).
// Swapped QK^T (lane owns one q-row's k-slice). Double-buffered K/V prefetch;
// sQ region (16KB) reused as the odd K/V buffers after Q-fragment hoist.
// exp2-domain softmax; defer-max (T13); uniform-mask fast path; setprio (T5).
// LDS (48KB): [0:8K) K1 | [8K:16K) V1 | [16K:24K) K0 | [24K:32K) V0 | [32K:48K) sP

__global__ __launch_bounds__(512, 4) void attn_fwd(
    const u16* __restrict__ Qm, const u16* __restrict__ Km,
    const u16* __restrict__ Vt, const u16* __restrict__ posb,
    const u32* __restrict__ mbits, u16* __restrict__ Om) {
  const int bb = blockIdx.x >> 3;
  const int qt = blockIdx.x & 7;
  const int h = blockIdx.y;
  const int t = threadIdx.x;
  const int w = t >> 6, lane = t & 63;
  const int lr = lane & 15, lg = lane >> 4;

  __shared__ __align__(16) char smem[49152];

  const int q0 = qt * 128;
  const size_t baseQ = ((size_t)bb * 1024) * 1024 + (size_t)h * 64;
  const size_t baseV = ((size_t)(bb * 16 + h) * 64) * 1024;
  const int qg = q0 + w * 16 + lr;
  const u16* posrow = posb + ((size_t)h * 1024 + qg) * 1024;
  const u32* mrow = mbits + ((size_t)bb * 1024 + qg) * 32;

  // stage Q (128x64, swizzled via source permutation) + kt=0 K/V into buf0
#pragma unroll
  for (int i = 0; i < 2; ++i) {
    const int idx = i * 512 + t;
    const int r = idx >> 3;
    const int w8 = idx & 7;
    gload_lds16(Qm + baseQ + (size_t)(q0 + r) * 1024 + (w8 ^ (r & 7)) * 8, smem + idx * 16);
  }
  {
    const int r = t >> 3;
    const int w8 = t & 7;
    gload_lds16(Km + baseQ + (size_t)r * 1024 + (w8 ^ (r & 7)) * 8, smem + 16384 + t * 16);
    gload_lds16(Vt + baseV + (size_t)r * 1024 + (w8 ^ (r & 7)) * 8, smem + 24576 + t * 16);
  }

  // uniform-mask scan (1 bit per k; all-ones rows skip masking entirely)
  u32 ok = 0xffffffffu;
#pragma unroll
  for (int i = 0; i < 8; ++i) {
    const uint4 m4 = *(const uint4*)&mrow[i * 4];
    ok &= m4.x & m4.y & m4.z & m4.w;
  }
  const bool allone = __all(ok == 0xffffffffu);

  uint2 pz[4];
#pragma unroll
  for (int n = 0; n < 4; ++n) pz[n] = *(const uint2*)&posrow[n * 16 + lg * 4];

  __syncthreads();  // Q + buf0 landed

  // hoist Q fragments (B-operand)
  bfrag qv[2];
#pragma unroll
  for (int ks = 0; ks < 2; ++ks) {
    const int byt = (w * 16 + lr) * 128 + ((ks * 64 + lg * 16) ^ ((lr & 7) << 4));
    qv[ks] = *(const bfrag*)(smem + byt);
  }
  __syncthreads();  // everyone hoisted; sQ region may be overwritten

  f32x4 o[4] = {};
  float m_q = -3.0e38f, l_q = 0.f;

  for (int kt = 0; kt < 16; ++kt) {
    const int cur = kt & 1;
    const char* sK = smem + (cur ? 0 : 16384);
    const char* sV = smem + (cur ? 8192 : 24576);

    uint2 pzn[4];
    if (kt < 15) {
      const int kn = (kt + 1) * 64;
      char* dK = smem + (cur ? 16384 : 0);
      char* dV = smem + (cur ? 24576 : 8192);
      const int r = t >> 3;
      const int w8 = t & 7;
      gload_lds16(Km + baseQ + (size_t)(kn + r) * 1024 + (w8 ^ (r & 7)) * 8, dK + t * 16);
      gload_lds16(Vt + baseV + (size_t)r * 1024 + kn + (w8 ^ (r & 7)) * 8, dV + t * 16);
#pragma unroll
      for (int n = 0; n < 4; ++n) pzn[n] = *(const uint2*)&posrow[kn + n * 16 + lg * 4];
    }

    // S^T[k][q] = mfma(K, Q); lane: k-local = n*16 + lg*4 + j, q = qg
    f32x4 s[4] = {};
    __builtin_amdgcn_s_setprio(1);
#pragma unroll
    for (int ks = 0; ks < 2; ++ks) {
#pragma unroll
      for (int n = 0; n < 4; ++n) {
        const int byt = (n * 16 + lr) * 128 + ((ks * 64 + lg * 16) ^ ((lr & 7) << 4));
        const bfrag kf = *(const bfrag*)(sK + byt);
        s[n] = __builtin_amdgcn_mfma_f32_16x16x32_bf16(kf, qv[ks], s[n], 0, 0, 0);
      }
    }
    __builtin_amdgcn_s_setprio(0);

    // pos add (exp2 domain: pos pre-scaled by log2e, Q by scl*log2e)
    float pv[16];
#pragma unroll
    for (int n = 0; n < 4; ++n) {
      pv[n * 4 + 0] = s[n][0] + bf2f((u16)(pz[n].x & 0xffff));
      pv[n * 4 + 1] = s[n][1] + bf2f((u16)(pz[n].x >> 16));
      pv[n * 4 + 2] = s[n][2] + bf2f((u16)(pz[n].y & 0xffff));
      pv[n * 4 + 3] = s[n][3] + bf2f((u16)(pz[n].y >> 16));
    }

    if (!allone) {   // wave-uniform; never taken for all-ones masks
      const u32 a0 = mrow[kt * 2], a1 = mrow[kt * 2 + 1];
#pragma unroll
      for (int n = 0; n < 4; ++n)
#pragma unroll
        for (int j = 0; j < 4; ++j) {
          const int kl = n * 16 + lg * 4 + j;
          const u32 mw = (kl & 32) ? a1 : a0;
          if (!((mw >> (kl & 31)) & 1u)) pv[n * 4 + j] = -1.0e9f;
        }
    }

    // max over 16 (v_max3 tree) + cross-group
    float tmax = fmax3(pv[0], pv[1], pv[2]);
    tmax = fmax3(tmax, pv[3], pv[4]);
    tmax = fmax3(tmax, pv[5], pv[6]);
    tmax = fmax3(tmax, pv[7], pv[8]);
    tmax = fmax3(tmax, pv[9], pv[10]);
    tmax = fmax3(tmax, pv[11], pv[12]);
    tmax = fmax3(tmax, pv[13], pv[14]);
    tmax = fmaxf(tmax, pv[15]);
    tmax = fmaxf(tmax, __shfl_xor(tmax, 16));
    tmax = fmaxf(tmax, __shfl_xor(tmax, 32));

    if (!__all(tmax <= m_q + 8.0f)) {       // defer-max (T13)
      const float mn = fmaxf(m_q, tmax);
      const float sc = __builtin_amdgcn_exp2f(m_q - mn);
      l_q *= sc;
#pragma unroll
      for (int j = 0; j < 4; ++j) {
        const float scj = __shfl(sc, lg * 4 + j);
#pragma unroll
        for (int n = 0; n < 4; ++n) o[n][j] *= scj;
      }
      m_q = mn;
    }
    float rs = 0.f;
#pragma unroll
    for (int i2 = 0; i2 < 16; ++i2) {
      pv[i2] = __builtin_amdgcn_exp2f(pv[i2] - m_q);
      rs += pv[i2];
    }
    rs += __shfl_xor(rs, 16);
    rs += __shfl_xor(rs, 32);
    l_q += rs;

    // P -> per-wave swizzled LDS, read back as A-fragment
    char* pbuf = smem + 32768 + w * 2048;
#pragma unroll
    for (int n = 0; n < 4; ++n) {
      uint2 pk;
      pk.x = cvtpk(pv[n * 4 + 0], pv[n * 4 + 1]);
      pk.y = cvtpk(pv[n * 4 + 2], pv[n * 4 + 3]);
      const int byt = lr * 128 + ((n * 32 + lg * 8) ^ ((lr & 7) << 4));
      *(uint2*)(pbuf + byt) = pk;
    }
    __builtin_amdgcn_s_setprio(1);
#pragma unroll
    for (int ks = 0; ks < 2; ++ks) {
      const int pbyt = lr * 128 + ((ks * 64 + lg * 16) ^ ((lr & 7) << 4));
      const bfrag pf = *(const bfrag*)(pbuf + pbyt);
#pragma unroll
      for (int n = 0; n < 4; ++n) {
        const int vb = (n * 16 + lr) * 128 + ((ks * 64 + lg * 16) ^ ((lr & 7) << 4));
        const bfrag vf = *(const bfrag*)(sV + vb);
        o[n] = __builtin_amdgcn_mfma_f32_16x16x32_bf16(pf, vf, o[n], 0, 0, 0);
      }
    }
    __builtin_amdgcn_s_setprio(0);

    __syncthreads();   // drains prefetch vmcnt; next buffers ready

    if (kt < 15) {
#pragma unroll
      for (int n = 0; n < 4; ++n) pz[n] = pzn[n];
    }
  }

  // normalize + write x_attn[b, q, h*64 + d]
#pragma unroll
  for (int j = 0; j < 4; ++j) {
    const float lj = __shfl(l_q, lg * 4 + j);
    const float inv = 1.f / lj;
    const int qr = q0 + w * 16 + lg * 4 + j;
#pragma unroll
    for (int n = 0; n < 4; ++n)
      Om[baseQ + (size_t)qr * 1024 + n * 16 + lr] = f2bf_hw(o[n][j] * inv);
  }
}

// ---------------- launch ----------------

extern "C" void kernel_launch(void* const* d_in, const int* in_sizes, int n_in,
                              void* d_out, int out_size, void* d_ws, size_t ws_size,
                              hipStream_t stream) {
  const float* query = (const float*)d_in[0];
  const float* key_  = (const float*)d_in[1];
  const float* value = (const float*)d_in[2];
  const int*   mask  = (const int*)d_in[3];
  const float* pos   = (const float*)d_in[4];
  const float* wq = (const float*)d_in[5];
  const float* bq = (const float*)d_in[6];
  const float* wk = (const float*)d_in[7];
  const float* bk = (const float*)d_in[8];
  const float* wv = (const float*)d_in[9];
  const float* bv = (const float*)d_in[10];
  const float* wo = (const float*)d_in[11];
  const float* bo = (const float*)d_in[12];

  char* ws = (char*)d_ws;
  const size_t MB = 1024 * 1024;
  u16* wqb  = (u16*)(ws + 0 * MB);
  u16* wkb  = (u16*)(ws + 2 * MB);
  u16* wvb  = (u16*)(ws + 4 * MB);
  u16* wob  = (u16*)(ws + 6 * MB);
  u16* posb = (u16*)(ws + 8 * MB);     // 32MB  [H,S,S] bf16 (pre-scaled by log2e)
  u16* Qb   = (u16*)(ws + 40 * MB);    // 16MB
  u16* Kb   = (u16*)(ws + 56 * MB);
  u16* Vtb  = (u16*)(ws + 72 * MB);    // 16MB  [B,H,64,S] bf16 (V transposed)
  u16* Xa   = (u16*)(ws + 88 * MB);
  u32* mb   = (u32*)(ws + 104 * MB);   // 1MB bitmask
  u16* wotb = (u16*)(ws + 105 * MB);   // 2MB  Wo^T bf16
  u16* W2b  = (u16*)(ws + 107 * MB);   // 2MB  (Wo@Wo) bf16
  float* bo2 = (float*)(ws + 109 * MB);            // 4KB

  const float log2e = 1.4426950408889634f;
  const float qs = 0.0883883476483184f * log2e;   // (1/sqrt(2*dk)) * log2e

  cast_v4<<<1024, 256, 0, stream>>>(wq, wqb, 262144, 1.0f);
  cast_v4<<<1024, 256, 0, stream>>>(wk, wkb, 262144, 1.0f);
  cast_v4<<<1024, 256, 0, stream>>>(wv, wvb, 262144, 1.0f);
  cast_v4<<<1024, 256, 0, stream>>>(wo, wob, 262144, 1.0f);
  cast_v4<<<16384, 256, 0, stream>>>(pos, posb, 4194304, log2e);
  pack_mask<<<1024, 256, 0, stream>>>(mask, mb);
  transpose_cast<<<dim3(16, 16), 256, 0, stream>>>(wo, wotb);
  bias2<<<256, 256, 0, stream>>>(wo, bo, bo2);

  // W2 = Wo @ Wo  (A = Wo bf16, W-input = Wo^T in [N][K] layout)
  gemm_bt_64<<<dim3(16, 16), 256, 0, stream>>>(wob, wotb, W2b, 1024, 1024);

  const dim3 gg(64, 8);
  gemm_bt_a32<u16><<<gg, 256, 0, stream>>>(query, wqb, bq, Qb, 8192, 1024, 1024, qs);
  gemm_bt_a32<u16><<<gg, 256, 0, stream>>>(key_,  wkb, bk, Kb, 8192, 1024, 1024, 1.0f);
  gemm_bt_a32_vt<<<gg, 256, 0, stream>>>(value, wvb, bv, Vtb, 8192, 1024, 1024);

  attn_fwd<<<dim3(64, 16), 512, 0, stream>>>(Qb, Kb, Vtb, posb, mb, Xa);

  // out = Xa @ W2^T + bo2   (folds the doubled output linear)
  gemm_bt_a16<float><<<gg, 256, 0, stream>>>(Xa, W2b, bo2, (float*)d_out, 8192, 1024, 1024);
}

// Round 5
// 260.846 us; speedup vs baseline: 1.6259x; 1.0990x over previous
//
#include <hip/hip_runtime.h>
#include <hip/hip_bf16.h>

typedef unsigned short u16;
typedef unsigned int u32;
typedef __attribute__((ext_vector_type(8))) short bfrag;   // 8 bf16 (4 VGPRs)
typedef __attribute__((ext_vector_type(4))) float f32x4;

#define DEVINL __device__ __forceinline__

DEVINL u16 f2bf(float f) {
  u32 u = __float_as_uint(f);
  u32 r = (u + 0x7fffu + ((u >> 16) & 1u)) >> 16;   // RNE
  return (u16)r;
}
DEVINL float bf2f(u16 u) { return __uint_as_float(((u32)u) << 16); }
// HW packed f32->bf16 (RNE), 1 inst for 2 elements
DEVINL u32 cvtpk(float lo, float hi) {
  u32 r;
  asm("v_cvt_pk_bf16_f32 %0, %1, %2" : "=v"(r) : "v"(lo), "v"(hi));
  return r;
}
DEVINL u16 f2bf_hw(float v) { return (u16)cvtpk(v, v); }
DEVINL float fmax3(float a, float b, float c) { return fmaxf(fmaxf(a, b), c); }  // fuses to v_max3_f32

DEVINL void gload_lds16(const void* g, void* l) {
  __builtin_amdgcn_global_load_lds(
      (const __attribute__((address_space(1))) void*)g,
      (__attribute__((address_space(3))) void*)l, 16, 0, 0);
}

DEVINL void storeC(u16* C, size_t idx, float v) { C[idx] = f2bf_hw(v); }
DEVINL void storeC(float* C, size_t idx, float v) { C[idx] = v; }

// ---------------- prep kernels ----------------

__global__ void cast_v4(const float* __restrict__ in, u16* __restrict__ out, int n4, float s) {
  const int i = blockIdx.x * 256 + threadIdx.x;
  if (i < n4) {
    const float4 f = ((const float4*)in)[i];
    uint2 r;
    r.x = cvtpk(f.x * s, f.y * s);
    r.y = cvtpk(f.z * s, f.w * s);
    ((uint2*)out)[i] = r;
  }
}

__global__ void pack_mask(const int* __restrict__ mask, u32* __restrict__ bits) {
  const size_t wi = (size_t)blockIdx.x * 256 + threadIdx.x;
  const int* src = mask + wi * 32;
  u32 v = 0;
#pragma unroll
  for (int i = 0; i < 8; ++i) {
    const int4 m4 = ((const int4*)src)[i];
    if (m4.x) v |= 1u << (i * 4 + 0);
    if (m4.y) v |= 1u << (i * 4 + 1);
    if (m4.z) v |= 1u << (i * 4 + 2);
    if (m4.w) v |= 1u << (i * 4 + 3);
  }
  bits[wi] = v;
}

// transpose-cast: out[j][k] = bf16(in[k][j]), 1024x1024, grid(16,16), 256 thr
__global__ void transpose_cast(const float* __restrict__ in, u16* __restrict__ out) {
  __shared__ u16 tile[64][65];
  const int t = threadIdx.x;
  const int bx = blockIdx.x, by = blockIdx.y;
#pragma unroll
  for (int p = 0; p < 4; ++p) {
    const int r = (t >> 4) + p * 16;
    const int c = (t & 15) * 4;
    const float4 f = *(const float4*)&in[(size_t)(by * 64 + r) * 1024 + bx * 64 + c];
    tile[c + 0][r] = f2bf(f.x);
    tile[c + 1][r] = f2bf(f.y);
    tile[c + 2][r] = f2bf(f.z);
    tile[c + 3][r] = f2bf(f.w);
  }
  __syncthreads();
#pragma unroll
  for (int p = 0; p < 4; ++p) {
    const int r = (t >> 4) + p * 16;
    const int c = (t & 15) * 4;
    uint2 v;
    v.x = (u32)tile[r][c] | ((u32)tile[r][c + 1] << 16);
    v.y = (u32)tile[r][c + 2] | ((u32)tile[r][c + 3] << 16);
    *(uint2*)&out[(size_t)(bx * 64 + r) * 1024 + by * 64 + c] = v;
  }
}

// bo2 = Wo @ bo + bo ; one wave per output row
__global__ void bias2(const float* __restrict__ wo, const float* __restrict__ bo,
                      float* __restrict__ bo2) {
  const int w = threadIdx.x >> 6, lane = threadIdx.x & 63;
  const int row = blockIdx.x * 4 + w;
  const float* src = wo + (size_t)row * 1024;
  float s = 0.f;
#pragma unroll
  for (int i = 0; i < 4; ++i) {
    const float4 f = *(const float4*)&src[lane * 4 + i * 256];
    const float4 g = *(const float4*)&bo[lane * 4 + i * 256];
    s += f.x * g.x + f.y * g.y + f.z * g.z + f.w * g.w;
  }
#pragma unroll
  for (int d = 1; d < 64; d <<= 1) s += __shfl_xor(s, d);
  if (lane == 0) bo2[row] = s + bo[row];
}

// small GEMM, 64x64 tile (for W2 = Wo@Wo): C = A @ W^T, no bias
__global__ __launch_bounds__(256) void gemm_bt_64(
    const u16* __restrict__ A, const u16* __restrict__ W,
    u16* __restrict__ C, int N, int K) {
  __shared__ u16 sA[64 * 64];
  __shared__ u16 sB[64 * 64];
  const int t = threadIdx.x;
  const int w = t >> 6, lane = t & 63;
  const int lr = lane & 15, lk = (lane >> 4) * 8;
  const int m0 = blockIdx.x * 64, n0 = blockIdx.y * 64;
  f32x4 acc[4] = {};
  for (int k0 = 0; k0 < K; k0 += 64) {
#pragma unroll
    for (int i = 0; i < 2; ++i) {
      const int idx = i * 256 + t;
      const int row = idx >> 3;
      const int col = (idx & 7) * 8;
      gload_lds16(A + (size_t)(m0 + row) * K + k0 + col, &sA[idx * 8]);
      gload_lds16(W + (size_t)(n0 + row) * K + k0 + col, &sB[idx * 8]);
    }
    __syncthreads();
#pragma unroll
    for (int ks = 0; ks < 2; ++ks) {
      const bfrag av = *(const bfrag*)&sA[(w * 16 + lr) * 64 + ks * 32 + lk];
#pragma unroll
      for (int n = 0; n < 4; ++n) {
        const bfrag bv = *(const bfrag*)&sB[(n * 16 + lr) * 64 + ks * 32 + lk];
        acc[n] = __builtin_amdgcn_mfma_f32_16x16x32_bf16(av, bv, acc[n], 0, 0, 0);
      }
    }
    __syncthreads();
  }
  const int orow = (lane >> 4) * 4;
#pragma unroll
  for (int n = 0; n < 4; ++n)
#pragma unroll
    for (int j = 0; j < 4; ++j)
      C[(size_t)(m0 + w * 16 + orow + j) * N + n0 + n * 16 + lr] = f2bf_hw(acc[n][j]);
}

// ---------------- GEMM: C[M,N] = (A[M,K] @ W[N,K]^T + bias) * oscale ----------------
// 128x128 tile, BK=64, 4 waves (2x2), each wave 64x64 = 4x4 frags of 16x16x32.
// T2 XOR-swizzle on both LDS tiles: slot (row, g) holds source col-group
// g ^ (row&7); fragment reads XOR the 16B column slot with (row&7)<<4.
// Kills the 16-way row-stride-128B bank conflict on ds_read_b128.

template <typename OutT>
__global__ __launch_bounds__(256) void gemm_bt_a16(
    const u16* __restrict__ A, const u16* __restrict__ W,
    const float* __restrict__ bias, OutT* __restrict__ C,
    int M, int N, int K) {
  __shared__ __align__(16) u16 sA[128 * 64];
  __shared__ __align__(16) u16 sB[128 * 64];
  const int t = threadIdx.x;
  const int w = t >> 6, lane = t & 63;
  const int lr = lane & 15, lg = lane >> 4;
  const int m0 = blockIdx.x * 128, n0 = blockIdx.y * 128;
  const int wr = (w >> 1) * 64, wc = (w & 1) * 64;
  f32x4 acc[4][4] = {};

  for (int k0 = 0; k0 < K; k0 += 64) {
#pragma unroll
    for (int i = 0; i < 4; ++i) {
      const int idx = i * 256 + t;
      const int row = idx >> 3;
      const int col = ((idx & 7) ^ (row & 7)) * 8;   // pre-swizzled source
      gload_lds16(A + (size_t)(m0 + row) * K + k0 + col, (char*)sA + idx * 16);
      gload_lds16(W + (size_t)(n0 + row) * K + k0 + col, (char*)sB + idx * 16);
    }
    __syncthreads();
#pragma unroll
    for (int ks = 0; ks < 2; ++ks) {
      bfrag av[4], bv[4];
#pragma unroll
      for (int m = 0; m < 4; ++m) {
        const int row = wr + m * 16 + lr;
        av[m] = *(const bfrag*)((const char*)sA + row * 128 + ((ks * 64 + lg * 16) ^ ((row & 7) << 4)));
      }
#pragma unroll
      for (int n = 0; n < 4; ++n) {
        const int row = wc + n * 16 + lr;
        bv[n] = *(const bfrag*)((const char*)sB + row * 128 + ((ks * 64 + lg * 16) ^ ((row & 7) << 4)));
      }
#pragma unroll
      for (int m = 0; m < 4; ++m)
#pragma unroll
        for (int n = 0; n < 4; ++n)
          acc[m][n] = __builtin_amdgcn_mfma_f32_16x16x32_bf16(av[m], bv[n], acc[m][n], 0, 0, 0);
    }
    __syncthreads();
  }

  float bz[4];
#pragma unroll
  for (int n = 0; n < 4; ++n) bz[n] = bias[n0 + wc + n * 16 + lr];
  const int orow = lg * 4;
#pragma unroll
  for (int m = 0; m < 4; ++m) {
#pragma unroll
    for (int n = 0; n < 4; ++n) {
      const int r = m0 + wr + m * 16 + orow;
      const int c = n0 + wc + n * 16 + lr;
#pragma unroll
      for (int j = 0; j < 4; ++j)
        storeC(C, (size_t)(r + j) * N + c, acc[m][n][j] + bz[n]);
    }
  }
}

// A fp32 (cast to bf16 on stage via v_cvt_pk, swizzled ds_write); output scale
template <typename OutT>
__global__ __launch_bounds__(256) void gemm_bt_a32(
    const float* __restrict__ A, const u16* __restrict__ W,
    const float* __restrict__ bias, OutT* __restrict__ C,
    int M, int N, int K, float oscale) {
  __shared__ __align__(16) u16 sA[128 * 64];
  __shared__ __align__(16) u16 sB[128 * 64];
  const int t = threadIdx.x;
  const int w = t >> 6, lane = t & 63;
  const int lr = lane & 15, lg = lane >> 4;
  const int m0 = blockIdx.x * 128, n0 = blockIdx.y * 128;
  const int wr = (w >> 1) * 64, wc = (w & 1) * 64;
  f32x4 acc[4][4] = {};

  for (int k0 = 0; k0 < K; k0 += 64) {
#pragma unroll
    for (int i = 0; i < 4; ++i) {
      const int idx = i * 256 + t;
      const int row = idx >> 3;
      const int cg = idx & 7;
      const float* src = A + (size_t)(m0 + row) * K + k0 + cg * 8;
      const float4 f0 = *(const float4*)src;
      const float4 f1 = *(const float4*)(src + 4);
      uint4 pk;
      pk.x = cvtpk(f0.x, f0.y);
      pk.y = cvtpk(f0.z, f0.w);
      pk.z = cvtpk(f1.x, f1.y);
      pk.w = cvtpk(f1.z, f1.w);
      *(uint4*)((char*)sA + row * 128 + ((cg ^ (row & 7)) * 16)) = pk;  // swizzled slot
      gload_lds16(W + (size_t)(n0 + row) * K + k0 + ((cg ^ (row & 7)) * 8), (char*)sB + idx * 16);
    }
    __syncthreads();
#pragma unroll
    for (int ks = 0; ks < 2; ++ks) {
      bfrag av[4], bv[4];
#pragma unroll
      for (int m = 0; m < 4; ++m) {
        const int row = wr + m * 16 + lr;
        av[m] = *(const bfrag*)((const char*)sA + row * 128 + ((ks * 64 + lg * 16) ^ ((row & 7) << 4)));
      }
#pragma unroll
      for (int n = 0; n < 4; ++n) {
        const int row = wc + n * 16 + lr;
        bv[n] = *(const bfrag*)((const char*)sB + row * 128 + ((ks * 64 + lg * 16) ^ ((row & 7) << 4)));
      }
#pragma unroll
      for (int m = 0; m < 4; ++m)
#pragma unroll
        for (int n = 0; n < 4; ++n)
          acc[m][n] = __builtin_amdgcn_mfma_f32_16x16x32_bf16(av[m], bv[n], acc[m][n], 0, 0, 0);
    }
    __syncthreads();
  }

  float bz[4];
#pragma unroll
  for (int n = 0; n < 4; ++n) bz[n] = bias[n0 + wc + n * 16 + lr];
  const int orow = lg * 4;
#pragma unroll
  for (int m = 0; m < 4; ++m) {
#pragma unroll
    for (int n = 0; n < 4; ++n) {
      const int r = m0 + wr + m * 16 + orow;
      const int c = n0 + wc + n * 16 + lr;
#pragma unroll
      for (int j = 0; j < 4; ++j)
        storeC(C, (size_t)(r + j) * N + c, (acc[m][n][j] + bz[n]) * oscale);
    }
  }
}

// V projection writing transposed output Vt[((b*16+h)*64 + d)*1024 + s]
__global__ __launch_bounds__(256) void gemm_bt_a32_vt(
    const float* __restrict__ A, const u16* __restrict__ W,
    const float* __restrict__ bias, u16* __restrict__ Vt,
    int M, int N, int K) {
  __shared__ __align__(16) u16 sA[128 * 64];
  __shared__ __align__(16) u16 sB[128 * 64];
  const int t = threadIdx.x;
  const int w = t >> 6, lane = t & 63;
  const int lr = lane & 15, lg = lane >> 4;
  const int m0 = blockIdx.x * 128, n0 = blockIdx.y * 128;
  const int wr = (w >> 1) * 64, wc = (w & 1) * 64;
  f32x4 acc[4][4] = {};

  for (int k0 = 0; k0 < K; k0 += 64) {
#pragma unroll
    for (int i = 0; i < 4; ++i) {
      const int idx = i * 256 + t;
      const int row = idx >> 3;
      const int cg = idx & 7;
      const float* src = A + (size_t)(m0 + row) * K + k0 + cg * 8;
      const float4 f0 = *(const float4*)src;
      const float4 f1 = *(const float4*)(src + 4);
      uint4 pk;
      pk.x = cvtpk(f0.x, f0.y);
      pk.y = cvtpk(f0.z, f0.w);
      pk.z = cvtpk(f1.x, f1.y);
      pk.w = cvtpk(f1.z, f1.w);
      *(uint4*)((char*)sA + row * 128 + ((cg ^ (row & 7)) * 16)) = pk;
      gload_lds16(W + (size_t)(n0 + row) * K + k0 + ((cg ^ (row & 7)) * 8), (char*)sB + idx * 16);
    }
    __syncthreads();
#pragma unroll
    for (int ks = 0; ks < 2; ++ks) {
      bfrag av[4], bv[4];
#pragma unroll
      for (int m = 0; m < 4; ++m) {
        const int row = wr + m * 16 + lr;
        av[m] = *(const bfrag*)((const char*)sA + row * 128 + ((ks * 64 + lg * 16) ^ ((row & 7) << 4)));
      }
#pragma unroll
      for (int n = 0; n < 4; ++n) {
        const int row = wc + n * 16 + lr;
        bv[n] = *(const bfrag*)((const char*)sB + row * 128 + ((ks * 64 + lg * 16) ^ ((row & 7) << 4)));
      }
#pragma unroll
      for (int m = 0; m < 4; ++m)
#pragma unroll
        for (int n = 0; n < 4; ++n)
          acc[m][n] = __builtin_amdgcn_mfma_f32_16x16x32_bf16(av[m], bv[n], acc[m][n], 0, 0, 0);
    }
    __syncthreads();
  }

  float bz[4];
#pragma unroll
  for (int n = 0; n < 4; ++n) bz[n] = bias[n0 + wc + n * 16 + lr];
  const int orow = lg * 4;
#pragma unroll
  for (int m = 0; m < 4; ++m) {
#pragma unroll
    for (int n = 0; n < 4; ++n) {
      const int r0 = m0 + wr + m * 16 + orow;        // global s-row base (mult of 4)
      const int c = n0 + wc + n * 16 + lr;            // global d-col
      const int bb = r0 >> 10, s = r0 & 1023;
      const int h = c >> 6, d = c & 63;
      uint2 v;
      v.x = cvtpk(acc[m][n][0] + bz[n], acc[m][n][1] + bz[n]);
      v.y = cvtpk(acc[m][n][2] + bz[n], acc[m][n][3] + bz[n]);
      *(uint2*)&Vt[(((size_t)bb * 16 + h) * 64 + d) * 1024 + s] = v;
    }
  }
}

// ---------------- attention ----------------
// block = (b, h, 128-row q-tile); 8 waves, wave w owns q-rows [w*16,(w+1)*16).
// Swapped QK^T (lane owns one q-row's k-slice). Double-buffered K/V prefetch;
// sQ region (16KB) reused as the odd K/V buffers after Q-fragment hoist.
// exp2-domain softmax; pos read as fp32 (log2e folded via FMA); defer-max;
// uniform-mask fast path; setprio (T5). All LDS tiles XOR-swizzled.
// LDS (48KB): [0:8K) K1 | [8K:16K) V1 | [16K:24K) K0 | [24K:32K) V0 | [32K:48K) sP

__global__ __launch_bounds__(512, 4) void attn_fwd(
    const u16* __restrict__ Qm, const u16* __restrict__ Km,
    const u16* __restrict__ Vt, const float* __restrict__ pos,
    const u32* __restrict__ mbits, u16* __restrict__ Om) {
  const int bb = blockIdx.x >> 3;
  const int qt = blockIdx.x & 7;
  const int h = blockIdx.y;
  const int t = threadIdx.x;
  const int w = t >> 6, lane = t & 63;
  const int lr = lane & 15, lg = lane >> 4;
  const float log2e = 1.4426950408889634f;

  __shared__ __align__(16) char smem[49152];

  const int q0 = qt * 128;
  const size_t baseQ = ((size_t)bb * 1024) * 1024 + (size_t)h * 64;
  const size_t baseV = ((size_t)(bb * 16 + h) * 64) * 1024;
  const int qg = q0 + w * 16 + lr;
  const float* posrow = pos + ((size_t)h * 1024 + qg) * 1024;
  const u32* mrow = mbits + ((size_t)bb * 1024 + qg) * 32;

  // stage Q (128x64, swizzled via source permutation) + kt=0 K/V into buf0
#pragma unroll
  for (int i = 0; i < 2; ++i) {
    const int idx = i * 512 + t;
    const int r = idx >> 3;
    const int w8 = idx & 7;
    gload_lds16(Qm + baseQ + (size_t)(q0 + r) * 1024 + (w8 ^ (r & 7)) * 8, smem + idx * 16);
  }
  {
    const int r = t >> 3;
    const int w8 = t & 7;
    gload_lds16(Km + baseQ + (size_t)r * 1024 + (w8 ^ (r & 7)) * 8, smem + 16384 + t * 16);
    gload_lds16(Vt + baseV + (size_t)r * 1024 + (w8 ^ (r & 7)) * 8, smem + 24576 + t * 16);
  }

  // uniform-mask scan (1 bit per k; all-ones rows skip masking entirely)
  u32 ok = 0xffffffffu;
#pragma unroll
  for (int i = 0; i < 8; ++i) {
    const uint4 m4 = *(const uint4*)&mrow[i * 4];
    ok &= m4.x & m4.y & m4.z & m4.w;
  }
  const bool allone = __all(ok == 0xffffffffu);

  float4 pz[4];
#pragma unroll
  for (int n = 0; n < 4; ++n) pz[n] = *(const float4*)&posrow[n * 16 + lg * 4];

  __syncthreads();  // Q + buf0 landed

  // hoist Q fragments (B-operand)
  bfrag qv[2];
#pragma unroll
  for (int ks = 0; ks < 2; ++ks) {
    const int byt = (w * 16 + lr) * 128 + ((ks * 64 + lg * 16) ^ ((lr & 7) << 4));
    qv[ks] = *(const bfrag*)(smem + byt);
  }
  __syncthreads();  // everyone hoisted; sQ region may be overwritten

  f32x4 o[4] = {};
  float m_q = -3.0e38f, l_q = 0.f;

  for (int kt = 0; kt < 16; ++kt) {
    const int cur = kt & 1;
    const char* sK = smem + (cur ? 0 : 16384);
    const char* sV = smem + (cur ? 8192 : 24576);

    float4 pzn[4];
    if (kt < 15) {
      const int kn = (kt + 1) * 64;
      char* dK = smem + (cur ? 16384 : 0);
      char* dV = smem + (cur ? 24576 : 8192);
      const int r = t >> 3;
      const int w8 = t & 7;
      gload_lds16(Km + baseQ + (size_t)(kn + r) * 1024 + (w8 ^ (r & 7)) * 8, dK + t * 16);
      gload_lds16(Vt + baseV + (size_t)r * 1024 + kn + (w8 ^ (r & 7)) * 8, dV + t * 16);
#pragma unroll
      for (int n = 0; n < 4; ++n) pzn[n] = *(const float4*)&posrow[kn + n * 16 + lg * 4];
    }

    // S^T[k][q] = mfma(K, Q); lane: k-local = n*16 + lg*4 + j, q = qg
    f32x4 s[4] = {};
    __builtin_amdgcn_s_setprio(1);
#pragma unroll
    for (int ks = 0; ks < 2; ++ks) {
#pragma unroll
      for (int n = 0; n < 4; ++n) {
        const int byt = (n * 16 + lr) * 128 + ((ks * 64 + lg * 16) ^ ((lr & 7) << 4));
        const bfrag kf = *(const bfrag*)(sK + byt);
        s[n] = __builtin_amdgcn_mfma_f32_16x16x32_bf16(kf, qv[ks], s[n], 0, 0, 0);
      }
    }
    __builtin_amdgcn_s_setprio(0);

    // pos add: pv = s + pos*log2e (fp32 pos, FMA)
    float pv[16];
#pragma unroll
    for (int n = 0; n < 4; ++n) {
      pv[n * 4 + 0] = fmaf(pz[n].x, log2e, s[n][0]);
      pv[n * 4 + 1] = fmaf(pz[n].y, log2e, s[n][1]);
      pv[n * 4 + 2] = fmaf(pz[n].z, log2e, s[n][2]);
      pv[n * 4 + 3] = fmaf(pz[n].w, log2e, s[n][3]);
    }

    if (!allone) {   // wave-uniform; never taken for all-ones masks
      const u32 a0 = mrow[kt * 2], a1 = mrow[kt * 2 + 1];
#pragma unroll
      for (int n = 0; n < 4; ++n)
#pragma unroll
        for (int j = 0; j < 4; ++j) {
          const int kl = n * 16 + lg * 4 + j;
          const u32 mw = (kl & 32) ? a1 : a0;
          if (!((mw >> (kl & 31)) & 1u)) pv[n * 4 + j] = -1.0e9f;
        }
    }

    // max over 16 (v_max3 tree) + cross-group
    float tmax = fmax3(pv[0], pv[1], pv[2]);
    tmax = fmax3(tmax, pv[3], pv[4]);
    tmax = fmax3(tmax, pv[5], pv[6]);
    tmax = fmax3(tmax, pv[7], pv[8]);
    tmax = fmax3(tmax, pv[9], pv[10]);
    tmax = fmax3(tmax, pv[11], pv[12]);
    tmax = fmax3(tmax, pv[13], pv[14]);
    tmax = fmaxf(tmax, pv[15]);
    tmax = fmaxf(tmax, __shfl_xor(tmax, 16));
    tmax = fmaxf(tmax, __shfl_xor(tmax, 32));

    if (!__all(tmax <= m_q + 8.0f)) {       // defer-max (T13)
      const float mn = fmaxf(m_q, tmax);
      const float sc = __builtin_amdgcn_exp2f(m_q - mn);
      l_q *= sc;
#pragma unroll
      for (int j = 0; j < 4; ++j) {
        const float scj = __shfl(sc, lg * 4 + j);
#pragma unroll
        for (int n = 0; n < 4; ++n) o[n][j] *= scj;
      }
      m_q = mn;
    }
    float rs = 0.f;
#pragma unroll
    for (int i2 = 0; i2 < 16; ++i2) {
      pv[i2] = __builtin_amdgcn_exp2f(pv[i2] - m_q);
      rs += pv[i2];
    }
    rs += __shfl_xor(rs, 16);
    rs += __shfl_xor(rs, 32);
    l_q += rs;

    // P -> per-wave swizzled LDS, read back as A-fragment
    char* pbuf = smem + 32768 + w * 2048;
#pragma unroll
    for (int n = 0; n < 4; ++n) {
      uint2 pk;
      pk.x = cvtpk(pv[n * 4 + 0], pv[n * 4 + 1]);
      pk.y = cvtpk(pv[n * 4 + 2], pv[n * 4 + 3]);
      const int byt = lr * 128 + ((n * 32 + lg * 8) ^ ((lr & 7) << 4));
      *(uint2*)(pbuf + byt) = pk;
    }
    __builtin_amdgcn_s_setprio(1);
#pragma unroll
    for (int ks = 0; ks < 2; ++ks) {
      const int pbyt = lr * 128 + ((ks * 64 + lg * 16) ^ ((lr & 7) << 4));
      const bfrag pf = *(const bfrag*)(pbuf + pbyt);
#pragma unroll
      for (int n = 0; n < 4; ++n) {
        const int vb = (n * 16 + lr) * 128 + ((ks * 64 + lg * 16) ^ ((lr & 7) << 4));
        const bfrag vf = *(const bfrag*)(sV + vb);
        o[n] = __builtin_amdgcn_mfma_f32_16x16x32_bf16(pf, vf, o[n], 0, 0, 0);
      }
    }
    __builtin_amdgcn_s_setprio(0);

    __syncthreads();   // drains prefetch vmcnt; next buffers ready

    if (kt < 15) {
#pragma unroll
      for (int n = 0; n < 4; ++n) pz[n] = pzn[n];
    }
  }

  // normalize + write x_attn[b, q, h*64 + d]
#pragma unroll
  for (int j = 0; j < 4; ++j) {
    const float lj = __shfl(l_q, lg * 4 + j);
    const float inv = 1.f / lj;
    const int qr = q0 + w * 16 + lg * 4 + j;
#pragma unroll
    for (int n = 0; n < 4; ++n)
      Om[baseQ + (size_t)qr * 1024 + n * 16 + lr] = f2bf_hw(o[n][j] * inv);
  }
}

// ---------------- launch ----------------

extern "C" void kernel_launch(void* const* d_in, const int* in_sizes, int n_in,
                              void* d_out, int out_size, void* d_ws, size_t ws_size,
                              hipStream_t stream) {
  const float* query = (const float*)d_in[0];
  const float* key_  = (const float*)d_in[1];
  const float* value = (const float*)d_in[2];
  const int*   mask  = (const int*)d_in[3];
  const float* pos   = (const float*)d_in[4];
  const float* wq = (const float*)d_in[5];
  const float* bq = (const float*)d_in[6];
  const float* wk = (const float*)d_in[7];
  const float* bk = (const float*)d_in[8];
  const float* wv = (const float*)d_in[9];
  const float* bv = (const float*)d_in[10];
  const float* wo = (const float*)d_in[11];
  const float* bo = (const float*)d_in[12];

  char* ws = (char*)d_ws;
  const size_t MB = 1024 * 1024;
  u16* wqb  = (u16*)(ws + 0 * MB);
  u16* wkb  = (u16*)(ws + 2 * MB);
  u16* wvb  = (u16*)(ws + 4 * MB);
  u16* wob  = (u16*)(ws + 6 * MB);
  u16* Qb   = (u16*)(ws + 40 * MB);    // 16MB
  u16* Kb   = (u16*)(ws + 56 * MB);
  u16* Vtb  = (u16*)(ws + 72 * MB);    // 16MB  [B,H,64,S] bf16 (V transposed)
  u16* Xa   = (u16*)(ws + 88 * MB);
  u32* mb   = (u32*)(ws + 104 * MB);   // 1MB bitmask
  u16* wotb = (u16*)(ws + 105 * MB);   // 2MB  Wo^T bf16
  u16* W2b  = (u16*)(ws + 107 * MB);   // 2MB  (Wo@Wo) bf16
  float* bo2 = (float*)(ws + 109 * MB);            // 4KB

  const float log2e = 1.4426950408889634f;
  const float qs = 0.0883883476483184f * log2e;   // (1/sqrt(2*dk)) * log2e

  cast_v4<<<1024, 256, 0, stream>>>(wq, wqb, 262144, 1.0f);
  cast_v4<<<1024, 256, 0, stream>>>(wk, wkb, 262144, 1.0f);
  cast_v4<<<1024, 256, 0, stream>>>(wv, wvb, 262144, 1.0f);
  cast_v4<<<1024, 256, 0, stream>>>(wo, wob, 262144, 1.0f);
  pack_mask<<<1024, 256, 0, stream>>>(mask, mb);
  transpose_cast<<<dim3(16, 16), 256, 0, stream>>>(wo, wotb);
  bias2<<<256, 256, 0, stream>>>(wo, bo, bo2);

  // W2 = Wo @ Wo  (A = Wo bf16, W-input = Wo^T in [N][K] layout)
  gemm_bt_64<<<dim3(16, 16), 256, 0, stream>>>(wob, wotb, W2b, 1024, 1024);

  const dim3 gg(64, 8);
  gemm_bt_a32<u16><<<gg, 256, 0, stream>>>(query, wqb, bq, Qb, 8192, 1024, 1024, qs);
  gemm_bt_a32<u16><<<gg, 256, 0, stream>>>(key_,  wkb, bk, Kb, 8192, 1024, 1024, 1.0f);
  gemm_bt_a32_vt<<<gg, 256, 0, stream>>>(value, wvb, bv, Vtb, 8192, 1024, 1024);

  attn_fwd<<<dim3(64, 16), 512, 0, stream>>>(Qb, Kb, Vtb, pos, mb, Xa);

  // out = Xa @ W2^T + bo2   (folds the doubled output linear)
  gemm_bt_a16<float><<<gg, 256, 0, stream>>>(Xa, W2b, bo2, (float*)d_out, 8192, 1024, 1024);
}

// Round 7
// 257.158 us; speedup vs baseline: 1.6492x; 1.0143x over previous
//
#include <hip/hip_runtime.h>
#include <hip/hip_bf16.h>

typedef unsigned short u16;
typedef unsigned int u32;
typedef __attribute__((ext_vector_type(8))) short bfrag;   // 8 bf16 (4 VGPRs)
typedef __attribute__((ext_vector_type(4))) float f32x4;

#define DEVINL __device__ __forceinline__

DEVINL u16 f2bf(float f) {
  u32 u = __float_as_uint(f);
  u32 r = (u + 0x7fffu + ((u >> 16) & 1u)) >> 16;   // RNE
  return (u16)r;
}
DEVINL float bf2f(u16 u) { return __uint_as_float(((u32)u) << 16); }
// HW packed f32->bf16 (RNE), 1 inst for 2 elements
DEVINL u32 cvtpk(float lo, float hi) {
  u32 r;
  asm("v_cvt_pk_bf16_f32 %0, %1, %2" : "=v"(r) : "v"(lo), "v"(hi));
  return r;
}
DEVINL u16 f2bf_hw(float v) { return (u16)cvtpk(v, v); }
DEVINL float fmax3(float a, float b, float c) { return fmaxf(fmaxf(a, b), c); }  // fuses to v_max3_f32

DEVINL void gload_lds16(const void* g, void* l) {
  __builtin_amdgcn_global_load_lds(
      (const __attribute__((address_space(1))) void*)g,
      (__attribute__((address_space(3))) void*)l, 16, 0, 0);
}

DEVINL void storeC(u16* C, size_t idx, float v) { C[idx] = f2bf_hw(v); }
DEVINL void storeC(float* C, size_t idx, float v) { C[idx] = v; }

#define SBAR0 __builtin_amdgcn_sched_barrier(0)

// ---------------- prep kernels ----------------

__global__ void cast_v4(const float* __restrict__ in, u16* __restrict__ out, int n4, float s) {
  const int i = blockIdx.x * 256 + threadIdx.x;
  if (i < n4) {
    const float4 f = ((const float4*)in)[i];
    uint2 r;
    r.x = cvtpk(f.x * s, f.y * s);
    r.y = cvtpk(f.z * s, f.w * s);
    ((uint2*)out)[i] = r;
  }
}

__global__ void pack_mask(const int* __restrict__ mask, u32* __restrict__ bits) {
  const size_t wi = (size_t)blockIdx.x * 256 + threadIdx.x;
  const int* src = mask + wi * 32;
  u32 v = 0;
#pragma unroll
  for (int i = 0; i < 8; ++i) {
    const int4 m4 = ((const int4*)src)[i];
    if (m4.x) v |= 1u << (i * 4 + 0);
    if (m4.y) v |= 1u << (i * 4 + 1);
    if (m4.z) v |= 1u << (i * 4 + 2);
    if (m4.w) v |= 1u << (i * 4 + 3);
  }
  bits[wi] = v;
}

// transpose-cast: out[j][k] = bf16(in[k][j]), 1024x1024, grid(16,16), 256 thr
__global__ void transpose_cast(const float* __restrict__ in, u16* __restrict__ out) {
  __shared__ u16 tile[64][65];
  const int t = threadIdx.x;
  const int bx = blockIdx.x, by = blockIdx.y;
#pragma unroll
  for (int p = 0; p < 4; ++p) {
    const int r = (t >> 4) + p * 16;
    const int c = (t & 15) * 4;
    const float4 f = *(const float4*)&in[(size_t)(by * 64 + r) * 1024 + bx * 64 + c];
    tile[c + 0][r] = f2bf(f.x);
    tile[c + 1][r] = f2bf(f.y);
    tile[c + 2][r] = f2bf(f.z);
    tile[c + 3][r] = f2bf(f.w);
  }
  __syncthreads();
#pragma unroll
  for (int p = 0; p < 4; ++p) {
    const int r = (t >> 4) + p * 16;
    const int c = (t & 15) * 4;
    uint2 v;
    v.x = (u32)tile[r][c] | ((u32)tile[r][c + 1] << 16);
    v.y = (u32)tile[r][c + 2] | ((u32)tile[r][c + 3] << 16);
    *(uint2*)&out[(size_t)(bx * 64 + r) * 1024 + by * 64 + c] = v;
  }
}

// bo2 = Wo @ bo + bo ; one wave per output row
__global__ void bias2(const float* __restrict__ wo, const float* __restrict__ bo,
                      float* __restrict__ bo2) {
  const int w = threadIdx.x >> 6, lane = threadIdx.x & 63;
  const int row = blockIdx.x * 4 + w;
  const float* src = wo + (size_t)row * 1024;
  float s = 0.f;
#pragma unroll
  for (int i = 0; i < 4; ++i) {
    const float4 f = *(const float4*)&src[lane * 4 + i * 256];
    const float4 g = *(const float4*)&bo[lane * 4 + i * 256];
    s += f.x * g.x + f.y * g.y + f.z * g.z + f.w * g.w;
  }
#pragma unroll
  for (int d = 1; d < 64; d <<= 1) s += __shfl_xor(s, d);
  if (lane == 0) bo2[row] = s + bo[row];
}

// small GEMM, 64x64 tile (for W2 = Wo@Wo): C = A @ W^T, no bias
__global__ __launch_bounds__(256) void gemm_bt_64(
    const u16* __restrict__ A, const u16* __restrict__ W,
    u16* __restrict__ C, int N, int K) {
  __shared__ u16 sA[64 * 64];
  __shared__ u16 sB[64 * 64];
  const int t = threadIdx.x;
  const int w = t >> 6, lane = t & 63;
  const int lr = lane & 15, lk = (lane >> 4) * 8;
  const int m0 = blockIdx.x * 64, n0 = blockIdx.y * 64;
  f32x4 acc[4] = {};
  for (int k0 = 0; k0 < K; k0 += 64) {
#pragma unroll
    for (int i = 0; i < 2; ++i) {
      const int idx = i * 256 + t;
      const int row = idx >> 3;
      const int col = (idx & 7) * 8;
      gload_lds16(A + (size_t)(m0 + row) * K + k0 + col, &sA[idx * 8]);
      gload_lds16(W + (size_t)(n0 + row) * K + k0 + col, &sB[idx * 8]);
    }
    __syncthreads();
#pragma unroll
    for (int ks = 0; ks < 2; ++ks) {
      const bfrag av = *(const bfrag*)&sA[(w * 16 + lr) * 64 + ks * 32 + lk];
#pragma unroll
      for (int n = 0; n < 4; ++n) {
        const bfrag bv = *(const bfrag*)&sB[(n * 16 + lr) * 64 + ks * 32 + lk];
        acc[n] = __builtin_amdgcn_mfma_f32_16x16x32_bf16(av, bv, acc[n], 0, 0, 0);
      }
    }
    __syncthreads();
  }
  const int orow = (lane >> 4) * 4;
#pragma unroll
  for (int n = 0; n < 4; ++n)
#pragma unroll
    for (int j = 0; j < 4; ++j)
      C[(size_t)(m0 + w * 16 + orow + j) * N + n0 + n * 16 + lr] = f2bf_hw(acc[n][j]);
}

// ---------------- GEMM: C[M,N] = (A[M,K] @ W[N,K]^T + bias) * oscale ----------------
// 128x128 tile, BK=64, 4 waves (2x2). T2 XOR-swizzled LDS + T3/T4: double-
// buffered, 1-ahead prefetch, ONE raw barrier per k-iter.

template <typename OutT>
__global__ __launch_bounds__(256) void gemm_bt_a16(
    const u16* __restrict__ A, const u16* __restrict__ W,
    const float* __restrict__ bias, OutT* __restrict__ C,
    int M, int N, int K) {
  __shared__ __align__(16) u16 sA[2][128 * 64];
  __shared__ __align__(16) u16 sB[2][128 * 64];
  const int t = threadIdx.x;
  const int w = t >> 6, lane = t & 63;
  const int lr = lane & 15, lg = lane >> 4;
  const int m0 = blockIdx.x * 128, n0 = blockIdx.y * 128;
  const int wr = (w >> 1) * 64, wc = (w & 1) * 64;
  f32x4 acc[4][4] = {};
  const int nk = K >> 6;

  // prologue: stage tile 0 into buf0
#pragma unroll
  for (int i = 0; i < 4; ++i) {
    const int idx = i * 256 + t;
    const int row = idx >> 3;
    const int col = ((idx & 7) ^ (row & 7)) * 8;   // pre-swizzled source
    gload_lds16(A + (size_t)(m0 + row) * K + col, (char*)sA[0] + idx * 16);
    gload_lds16(W + (size_t)(n0 + row) * K + col, (char*)sB[0] + idx * 16);
  }
  SBAR0; asm volatile("s_waitcnt vmcnt(0)" ::: "memory"); SBAR0;
  __builtin_amdgcn_s_barrier(); SBAR0;

#pragma unroll 2
  for (int kt = 0; kt < nk; ++kt) {
    const int cur = kt & 1;
    if (kt < nk - 1) {      // prefetch next tile into the other buffer
      const int k0 = (kt + 1) * 64;
#pragma unroll
      for (int i = 0; i < 4; ++i) {
        const int idx = i * 256 + t;
        const int row = idx >> 3;
        const int col = ((idx & 7) ^ (row & 7)) * 8;
        gload_lds16(A + (size_t)(m0 + row) * K + k0 + col, (char*)sA[cur ^ 1] + idx * 16);
        gload_lds16(W + (size_t)(n0 + row) * K + k0 + col, (char*)sB[cur ^ 1] + idx * 16);
      }
    }
    const char* pA = (const char*)sA[cur];
    const char* pB = (const char*)sB[cur];
#pragma unroll
    for (int ks = 0; ks < 2; ++ks) {
      bfrag av[4], bv[4];
#pragma unroll
      for (int m = 0; m < 4; ++m) {
        const int row = wr + m * 16 + lr;
        av[m] = *(const bfrag*)(pA + row * 128 + ((ks * 64 + lg * 16) ^ ((row & 7) << 4)));
      }
#pragma unroll
      for (int n = 0; n < 4; ++n) {
        const int row = wc + n * 16 + lr;
        bv[n] = *(const bfrag*)(pB + row * 128 + ((ks * 64 + lg * 16) ^ ((row & 7) << 4)));
      }
#pragma unroll
      for (int m = 0; m < 4; ++m)
#pragma unroll
        for (int n = 0; n < 4; ++n)
          acc[m][n] = __builtin_amdgcn_mfma_f32_16x16x32_bf16(av[m], bv[n], acc[m][n], 0, 0, 0);
    }
    if (kt < nk - 1) {
      SBAR0; asm volatile("s_waitcnt vmcnt(0)" ::: "memory"); SBAR0;
      __builtin_amdgcn_s_barrier(); SBAR0;
    }
  }

  float bz[4];
#pragma unroll
  for (int n = 0; n < 4; ++n) bz[n] = bias[n0 + wc + n * 16 + lr];
  const int orow = lg * 4;
#pragma unroll
  for (int m = 0; m < 4; ++m) {
#pragma unroll
    for (int n = 0; n < 4; ++n) {
      const int r = m0 + wr + m * 16 + orow;
      const int c = n0 + wc + n * 16 + lr;
#pragma unroll
      for (int j = 0; j < 4; ++j)
        storeC(C, (size_t)(r + j) * N + c, acc[m][n][j] + bz[n]);
    }
  }
}

// A fp32: T14 split — A_{t+1} global->regs issued early, cvt+ds_write after
// compute; W via gload_lds 1-ahead. One barrier/iter.
template <typename OutT>
__global__ __launch_bounds__(256) void gemm_bt_a32(
    const float* __restrict__ A, const u16* __restrict__ W,
    const float* __restrict__ bias, OutT* __restrict__ C,
    int M, int N, int K, float oscale) {
  __shared__ __align__(16) u16 sA[2][128 * 64];
  __shared__ __align__(16) u16 sB[2][128 * 64];
  const int t = threadIdx.x;
  const int w = t >> 6, lane = t & 63;
  const int lr = lane & 15, lg = lane >> 4;
  const int m0 = blockIdx.x * 128, n0 = blockIdx.y * 128;
  const int wr = (w >> 1) * 64, wc = (w & 1) * 64;
  f32x4 acc[4][4] = {};
  const int nk = K >> 6;

  // prologue: stage tile 0
#pragma unroll
  for (int i = 0; i < 4; ++i) {
    const int idx = i * 256 + t;
    const int row = idx >> 3;
    const int cg = idx & 7;
    const float* src = A + (size_t)(m0 + row) * K + cg * 8;
    const f32x4 f0 = *(const f32x4*)src;
    const f32x4 f1 = *(const f32x4*)(src + 4);
    uint4 pk;
    pk.x = cvtpk(f0[0], f0[1]);
    pk.y = cvtpk(f0[2], f0[3]);
    pk.z = cvtpk(f1[0], f1[1]);
    pk.w = cvtpk(f1[2], f1[3]);
    *(uint4*)((char*)sA[0] + row * 128 + ((cg ^ (row & 7)) * 16)) = pk;
    gload_lds16(W + (size_t)(n0 + row) * K + ((cg ^ (row & 7)) * 8), (char*)sB[0] + idx * 16);
  }
  SBAR0; asm volatile("s_waitcnt vmcnt(0) lgkmcnt(0)" ::: "memory"); SBAR0;
  __builtin_amdgcn_s_barrier(); SBAR0;

#pragma unroll 2
  for (int kt = 0; kt < nk; ++kt) {
    const int cur = kt & 1;
    f32x4 fa[4][2];
    if (kt < nk - 1) {      // issue next A-tile loads (regs) + W gload_lds early
      const int k0 = (kt + 1) * 64;
#pragma unroll
      for (int i = 0; i < 4; ++i) {
        const int idx = i * 256 + t;
        const int row = idx >> 3;
        const int cg = idx & 7;
        const float* src = A + (size_t)(m0 + row) * K + k0 + cg * 8;
        fa[i][0] = *(const f32x4*)src;
        fa[i][1] = *(const f32x4*)(src + 4);
      }
#pragma unroll
      for (int i = 0; i < 4; ++i) {
        const int idx = i * 256 + t;
        const int row = idx >> 3;
        const int cg = idx & 7;
        gload_lds16(W + (size_t)(n0 + row) * K + k0 + ((cg ^ (row & 7)) * 8),
                    (char*)sB[cur ^ 1] + idx * 16);
      }
    }
    const char* pA = (const char*)sA[cur];
    const char* pB = (const char*)sB[cur];
#pragma unroll
    for (int ks = 0; ks < 2; ++ks) {
      bfrag av[4], bv[4];
#pragma unroll
      for (int m = 0; m < 4; ++m) {
        const int row = wr + m * 16 + lr;
        av[m] = *(const bfrag*)(pA + row * 128 + ((ks * 64 + lg * 16) ^ ((row & 7) << 4)));
      }
#pragma unroll
      for (int n = 0; n < 4; ++n) {
        const int row = wc + n * 16 + lr;
        bv[n] = *(const bfrag*)(pB + row * 128 + ((ks * 64 + lg * 16) ^ ((row & 7) << 4)));
      }
#pragma unroll
      for (int m = 0; m < 4; ++m)
#pragma unroll
        for (int n = 0; n < 4; ++n)
          acc[m][n] = __builtin_amdgcn_mfma_f32_16x16x32_bf16(av[m], bv[n], acc[m][n], 0, 0, 0);
    }
    if (kt < nk - 1) {      // cvt + swizzled ds_write of next A-tile
#pragma unroll
      for (int i = 0; i < 4; ++i) {
        const int idx = i * 256 + t;
        const int row = idx >> 3;
        const int cg = idx & 7;
        uint4 pk;
        pk.x = cvtpk(fa[i][0][0], fa[i][0][1]);
        pk.y = cvtpk(fa[i][0][2], fa[i][0][3]);
        pk.z = cvtpk(fa[i][1][0], fa[i][1][1]);
        pk.w = cvtpk(fa[i][1][2], fa[i][1][3]);
        *(uint4*)((char*)sA[cur ^ 1] + row * 128 + ((cg ^ (row & 7)) * 16)) = pk;
      }
      SBAR0; asm volatile("s_waitcnt vmcnt(0) lgkmcnt(0)" ::: "memory"); SBAR0;
      __builtin_amdgcn_s_barrier(); SBAR0;
    }
  }

  float bz[4];
#pragma unroll
  for (int n = 0; n < 4; ++n) bz[n] = bias[n0 + wc + n * 16 + lr];
  const int orow = lg * 4;
#pragma unroll
  for (int m = 0; m < 4; ++m) {
#pragma unroll
    for (int n = 0; n < 4; ++n) {
      const int r = m0 + wr + m * 16 + orow;
      const int c = n0 + wc + n * 16 + lr;
#pragma unroll
      for (int j = 0; j < 4; ++j)
        storeC(C, (size_t)(r + j) * N + c, (acc[m][n][j] + bz[n]) * oscale);
    }
  }
}

// V projection writing transposed output Vt[((b*16+h)*64 + d)*1024 + s]
__global__ __launch_bounds__(256) void gemm_bt_a32_vt(
    const float* __restrict__ A, const u16* __restrict__ W,
    const float* __restrict__ bias, u16* __restrict__ Vt,
    int M, int N, int K) {
  __shared__ __align__(16) u16 sA[2][128 * 64];
  __shared__ __align__(16) u16 sB[2][128 * 64];
  const int t = threadIdx.x;
  const int w = t >> 6, lane = t & 63;
  const int lr = lane & 15, lg = lane >> 4;
  const int m0 = blockIdx.x * 128, n0 = blockIdx.y * 128;
  const int wr = (w >> 1) * 64, wc = (w & 1) * 64;
  f32x4 acc[4][4] = {};
  const int nk = K >> 6;

#pragma unroll
  for (int i = 0; i < 4; ++i) {
    const int idx = i * 256 + t;
    const int row = idx >> 3;
    const int cg = idx & 7;
    const float* src = A + (size_t)(m0 + row) * K + cg * 8;
    const f32x4 f0 = *(const f32x4*)src;
    const f32x4 f1 = *(const f32x4*)(src + 4);
    uint4 pk;
    pk.x = cvtpk(f0[0], f0[1]);
    pk.y = cvtpk(f0[2], f0[3]);
    pk.z = cvtpk(f1[0], f1[1]);
    pk.w = cvtpk(f1[2], f1[3]);
    *(uint4*)((char*)sA[0] + row * 128 + ((cg ^ (row & 7)) * 16)) = pk;
    gload_lds16(W + (size_t)(n0 + row) * K + ((cg ^ (row & 7)) * 8), (char*)sB[0] + idx * 16);
  }
  SBAR0; asm volatile("s_waitcnt vmcnt(0) lgkmcnt(0)" ::: "memory"); SBAR0;
  __builtin_amdgcn_s_barrier(); SBAR0;

#pragma unroll 2
  for (int kt = 0; kt < nk; ++kt) {
    const int cur = kt & 1;
    f32x4 fa[4][2];
    if (kt < nk - 1) {
      const int k0 = (kt + 1) * 64;
#pragma unroll
      for (int i = 0; i < 4; ++i) {
        const int idx = i * 256 + t;
        const int row = idx >> 3;
        const int cg = idx & 7;
        const float* src = A + (size_t)(m0 + row) * K + k0 + cg * 8;
        fa[i][0] = *(const f32x4*)src;
        fa[i][1] = *(const f32x4*)(src + 4);
      }
#pragma unroll
      for (int i = 0; i < 4; ++i) {
        const int idx = i * 256 + t;
        const int row = idx >> 3;
        const int cg = idx & 7;
        gload_lds16(W + (size_t)(n0 + row) * K + k0 + ((cg ^ (row & 7)) * 8),
                    (char*)sB[cur ^ 1] + idx * 16);
      }
    }
    const char* pA = (const char*)sA[cur];
    const char* pB = (const char*)sB[cur];
#pragma unroll
    for (int ks = 0; ks < 2; ++ks) {
      bfrag av[4], bv[4];
#pragma unroll
      for (int m = 0; m < 4; ++m) {
        const int row = wr + m * 16 + lr;
        av[m] = *(const bfrag*)(pA + row * 128 + ((ks * 64 + lg * 16) ^ ((row & 7) << 4)));
      }
#pragma unroll
      for (int n = 0; n < 4; ++n) {
        const int row = wc + n * 16 + lr;
        bv[n] = *(const bfrag*)(pB + row * 128 + ((ks * 64 + lg * 16) ^ ((row & 7) << 4)));
      }
#pragma unroll
      for (int m = 0; m < 4; ++m)
#pragma unroll
        for (int n = 0; n < 4; ++n)
          acc[m][n] = __builtin_amdgcn_mfma_f32_16x16x32_bf16(av[m], bv[n], acc[m][n], 0, 0, 0);
    }
    if (kt < nk - 1) {
#pragma unroll
      for (int i = 0; i < 4; ++i) {
        const int idx = i * 256 + t;
        const int row = idx >> 3;
        const int cg = idx & 7;
        uint4 pk;
        pk.x = cvtpk(fa[i][0][0], fa[i][0][1]);
        pk.y = cvtpk(fa[i][0][2], fa[i][0][3]);
        pk.z = cvtpk(fa[i][1][0], fa[i][1][1]);
        pk.w = cvtpk(fa[i][1][2], fa[i][1][3]);
        *(uint4*)((char*)sA[cur ^ 1] + row * 128 + ((cg ^ (row & 7)) * 16)) = pk;
      }
      SBAR0; asm volatile("s_waitcnt vmcnt(0) lgkmcnt(0)" ::: "memory"); SBAR0;
      __builtin_amdgcn_s_barrier(); SBAR0;
    }
  }

  float bz[4];
#pragma unroll
  for (int n = 0; n < 4; ++n) bz[n] = bias[n0 + wc + n * 16 + lr];
  const int orow = lg * 4;
#pragma unroll
  for (int m = 0; m < 4; ++m) {
#pragma unroll
    for (int n = 0; n < 4; ++n) {
      const int r0 = m0 + wr + m * 16 + orow;
      const int c = n0 + wc + n * 16 + lr;
      const int bb = r0 >> 10, s = r0 & 1023;
      const int h = c >> 6, d = c & 63;
      uint2 v;
      v.x = cvtpk(acc[m][n][0] + bz[n], acc[m][n][1] + bz[n]);
      v.y = cvtpk(acc[m][n][2] + bz[n], acc[m][n][3] + bz[n]);
      *(uint2*)&Vt[(((size_t)bb * 16 + h) * 64 + d) * 1024 + s] = v;
    }
  }
}

// ---------------- attention ----------------
// block = (b, h, 128-row q-tile); 8 waves. Swapped QK^T; T3/T4 pipeline:
// 3-buffer K/V, 2-tile-deep prefetch, counted vmcnt (never 0 in loop), ONE
// raw barrier per iter. exp2 softmax (fp32 pos via FMA), defer-max (T13),
// uniform-mask fast path, setprio (T5), XOR-swizzled tiles.
// LDS (80KB): [0:16K) sQ | [16K:40K) K x3 | [40K:64K) V x3 | [64K:80K) sP

__global__ __launch_bounds__(512, 4) void attn_fwd(
    const u16* __restrict__ Qm, const u16* __restrict__ Km,
    const u16* __restrict__ Vt, const float* __restrict__ pos,
    const u32* __restrict__ mbits, u16* __restrict__ Om) {
  const int bb = blockIdx.x >> 3;
  const int qt = blockIdx.x & 7;
  const int h = blockIdx.y;
  const int t = threadIdx.x;
  const int w = t >> 6, lane = t & 63;
  const int lr = lane & 15, lg = lane >> 4;
  const float log2e = 1.4426950408889634f;

  __shared__ __align__(16) char smem[81920];

  const int q0 = qt * 128;
  const size_t baseQ = ((size_t)bb * 1024) * 1024 + (size_t)h * 64;
  const size_t baseV = ((size_t)(bb * 16 + h) * 64) * 1024;
  const int qg = q0 + w * 16 + lr;
  const float* posrow = pos + ((size_t)h * 1024 + qg) * 1024;
  const u32* mrow = mbits + ((size_t)bb * 1024 + qg) * 32;
  const int sr = t >> 3, sw8 = t & 7;
  const int scol = (sw8 ^ (sr & 7)) * 8;   // pre-swizzled source column

  // prologue: Q (2 chunks/thread), tiles 0 and 1, mask, pos row 0
#pragma unroll
  for (int i = 0; i < 2; ++i) {
    const int idx = i * 512 + t;
    const int r = idx >> 3;
    gload_lds16(Qm + baseQ + (size_t)(q0 + r) * 1024 + ((idx & 7) ^ (r & 7)) * 8, smem + idx * 16);
  }
  gload_lds16(Km + baseQ + (size_t)sr * 1024 + scol, smem + 16384 + t * 16);
  gload_lds16(Vt + baseV + (size_t)sr * 1024 + scol, smem + 40960 + t * 16);
  gload_lds16(Km + baseQ + (size_t)(64 + sr) * 1024 + scol, smem + 24576 + t * 16);
  gload_lds16(Vt + baseV + (size_t)sr * 1024 + 64 + scol, smem + 49152 + t * 16);

  uint4 mraw[8];
#pragma unroll
  for (int i = 0; i < 8; ++i) mraw[i] = *(const uint4*)&mrow[i * 4];
  float4 pz[4];
#pragma unroll
  for (int n = 0; n < 4; ++n) pz[n] = *(const float4*)&posrow[n * 16 + lg * 4];

  u32 ok = 0xffffffffu;
#pragma unroll
  for (int i = 0; i < 8; ++i) ok &= mraw[i].x & mraw[i].y & mraw[i].z & mraw[i].w;
  const bool allone = __all(ok == 0xffffffffu);

  SBAR0; asm volatile("s_waitcnt vmcnt(4)" ::: "memory"); SBAR0;   // Q+tile0 landed
  __builtin_amdgcn_s_barrier(); SBAR0;

  // hoist Q fragments (sQ never overwritten -> no barrier after)
  bfrag qv[2];
#pragma unroll
  for (int ks = 0; ks < 2; ++ks) {
    const int byt = (w * 16 + lr) * 128 + ((ks * 64 + lg * 16) ^ ((lr & 7) << 4));
    qv[ks] = *(const bfrag*)(smem + byt);
  }

  f32x4 o[4] = {};
  float m_q = -3.0e38f, l_q = 0.f;
  char* pbuf = smem + 65536 + w * 2048;

#pragma unroll
  for (int kt = 0; kt < 16; ++kt) {
    const int cb = kt % 3;
    const char* sK = smem + 16384 + cb * 8192;
    const char* sV = smem + 40960 + cb * 8192;

    // 2-ahead K/V prefetch (waited 2 iters later -> fully hidden)
    if (kt < 14) {
      const int kn = (kt + 2) * 64;
      const int db = (kt + 2) % 3;
      gload_lds16(Km + baseQ + (size_t)(kn + sr) * 1024 + scol, smem + 16384 + db * 8192 + t * 16);
      gload_lds16(Vt + baseV + (size_t)sr * 1024 + kn + scol, smem + 40960 + db * 8192 + t * 16);
    }
    float4 pzn[4];
    if (kt < 15) {
      const int kn = (kt + 1) * 64;
#pragma unroll
      for (int n = 0; n < 4; ++n) pzn[n] = *(const float4*)&posrow[kn + n * 16 + lg * 4];
    }

    // S^T[k][q] = mfma(K, Q)
    f32x4 s[4] = {};
    __builtin_amdgcn_s_setprio(1);
#pragma unroll
    for (int ks = 0; ks < 2; ++ks) {
#pragma unroll
      for (int n = 0; n < 4; ++n) {
        const int byt = (n * 16 + lr) * 128 + ((ks * 64 + lg * 16) ^ ((lr & 7) << 4));
        const bfrag kf = *(const bfrag*)(sK + byt);
        s[n] = __builtin_amdgcn_mfma_f32_16x16x32_bf16(kf, qv[ks], s[n], 0, 0, 0);
      }
    }
    __builtin_amdgcn_s_setprio(0);

    // pos add (exp2 domain)
    float pv[16];
#pragma unroll
    for (int n = 0; n < 4; ++n) {
      pv[n * 4 + 0] = fmaf(pz[n].x, log2e, s[n][0]);
      pv[n * 4 + 1] = fmaf(pz[n].y, log2e, s[n][1]);
      pv[n * 4 + 2] = fmaf(pz[n].z, log2e, s[n][2]);
      pv[n * 4 + 3] = fmaf(pz[n].w, log2e, s[n][3]);
    }

    if (!allone) {   // wave-uniform; not taken for all-ones masks
      const u32 a0 = mrow[kt * 2], a1 = mrow[kt * 2 + 1];
#pragma unroll
      for (int n = 0; n < 4; ++n)
#pragma unroll
        for (int j = 0; j < 4; ++j) {
          const int kl = n * 16 + lg * 4 + j;
          const u32 mw = (kl & 32) ? a1 : a0;
          if (!((mw >> (kl & 31)) & 1u)) pv[n * 4 + j] = -1.0e9f;
        }
    }

    float tmax = fmax3(pv[0], pv[1], pv[2]);
    tmax = fmax3(tmax, pv[3], pv[4]);
    tmax = fmax3(tmax, pv[5], pv[6]);
    tmax = fmax3(tmax, pv[7], pv[8]);
    tmax = fmax3(tmax, pv[9], pv[10]);
    tmax = fmax3(tmax, pv[11], pv[12]);
    tmax = fmax3(tmax, pv[13], pv[14]);
    tmax = fmaxf(tmax, pv[15]);
    tmax = fmaxf(tmax, __shfl_xor(tmax, 16));
    tmax = fmaxf(tmax, __shfl_xor(tmax, 32));

    if (!__all(tmax <= m_q + 8.0f)) {       // defer-max (T13)
      const float mn = fmaxf(m_q, tmax);
      const float sc = __builtin_amdgcn_exp2f(m_q - mn);
      l_q *= sc;
#pragma unroll
      for (int j = 0; j < 4; ++j) {
        const float scj = __shfl(sc, lg * 4 + j);
#pragma unroll
        for (int n = 0; n < 4; ++n) o[n][j] *= scj;
      }
      m_q = mn;
    }
    float rs = 0.f;
#pragma unroll
    for (int i2 = 0; i2 < 16; ++i2) {
      pv[i2] = __builtin_amdgcn_exp2f(pv[i2] - m_q);
      rs += pv[i2];
    }
    rs += __shfl_xor(rs, 16);
    rs += __shfl_xor(rs, 32);
    l_q += rs;

    // P -> per-wave swizzled LDS, read back as A-fragment
#pragma unroll
    for (int n = 0; n < 4; ++n) {
      uint2 pk;
      pk.x = cvtpk(pv[n * 4 + 0], pv[n * 4 + 1]);
      pk.y = cvtpk(pv[n * 4 + 2], pv[n * 4 + 3]);
      const int byt = lr * 128 + ((n * 32 + lg * 8) ^ ((lr & 7) << 4));
      *(uint2*)(pbuf + byt) = pk;
    }
    __builtin_amdgcn_s_setprio(1);
#pragma unroll
    for (int ks = 0; ks < 2; ++ks) {
      const int pbyt = lr * 128 + ((ks * 64 + lg * 16) ^ ((lr & 7) << 4));
      const bfrag pf = *(const bfrag*)(pbuf + pbyt);
#pragma unroll
      for (int n = 0; n < 4; ++n) {
        const int vb = (n * 16 + lr) * 128 + ((ks * 64 + lg * 16) ^ ((lr & 7) << 4));
        const bfrag vf = *(const bfrag*)(sV + vb);
        o[n] = __builtin_amdgcn_mfma_f32_16x16x32_bf16(pf, vf, o[n], 0, 0, 0);
      }
    }
    __builtin_amdgcn_s_setprio(0);

    // end-of-iter: counted drain (tile kt+1 landed; kt+2 stays in flight)
    if (kt < 15) {
      SBAR0;
      if (kt < 14) asm volatile("s_waitcnt vmcnt(6)" ::: "memory");
      else         asm volatile("s_waitcnt vmcnt(4)" ::: "memory");
      SBAR0;
      __builtin_amdgcn_s_barrier();
      SBAR0;
#pragma unroll
      for (int n = 0; n < 4; ++n) pz[n] = pzn[n];
    }
  }

  // normalize + write x_attn[b, q, h*64 + d]
#pragma unroll
  for (int j = 0; j < 4; ++j) {
    const float lj = __shfl(l_q, lg * 4 + j);
    const float inv = 1.f / lj;
    const int qr = q0 + w * 16 + lg * 4 + j;
#pragma unroll
    for (int n = 0; n < 4; ++n)
      Om[baseQ + (size_t)qr * 1024 + n * 16 + lr] = f2bf_hw(o[n][j] * inv);
  }
}

// ---------------- launch ----------------

extern "C" void kernel_launch(void* const* d_in, const int* in_sizes, int n_in,
                              void* d_out, int out_size, void* d_ws, size_t ws_size,
                              hipStream_t stream) {
  const float* query = (const float*)d_in[0];
  const float* key_  = (const float*)d_in[1];
  const float* value = (const float*)d_in[2];
  const int*   mask  = (const int*)d_in[3];
  const float* pos   = (const float*)d_in[4];
  const float* wq = (const float*)d_in[5];
  const float* bq = (const float*)d_in[6];
  const float* wk = (const float*)d_in[7];
  const float* bk = (const float*)d_in[8];
  const float* wv = (const float*)d_in[9];
  const float* bv = (const float*)d_in[10];
  const float* wo = (const float*)d_in[11];
  const float* bo = (const float*)d_in[12];

  char* ws = (char*)d_ws;
  const size_t MB = 1024 * 1024;
  u16* wqb  = (u16*)(ws + 0 * MB);
  u16* wkb  = (u16*)(ws + 2 * MB);
  u16* wvb  = (u16*)(ws + 4 * MB);
  u16* wob  = (u16*)(ws + 6 * MB);
  u16* Qb   = (u16*)(ws + 40 * MB);    // 16MB
  u16* Kb   = (u16*)(ws + 56 * MB);
  u16* Vtb  = (u16*)(ws + 72 * MB);    // 16MB  [B,H,64,S] bf16 (V transposed)
  u16* Xa   = (u16*)(ws + 88 * MB);
  u32* mb   = (u32*)(ws + 104 * MB);   // 1MB bitmask
  u16* wotb = (u16*)(ws + 105 * MB);   // 2MB  Wo^T bf16
  u16* W2b  = (u16*)(ws + 107 * MB);   // 2MB  (Wo@Wo) bf16
  float* bo2 = (float*)(ws + 109 * MB);            // 4KB

  const float log2e = 1.4426950408889634f;
  const float qs = 0.0883883476483184f * log2e;   // (1/sqrt(2*dk)) * log2e

  cast_v4<<<1024, 256, 0, stream>>>(wq, wqb, 262144, 1.0f);
  cast_v4<<<1024, 256, 0, stream>>>(wk, wkb, 262144, 1.0f);
  cast_v4<<<1024, 256, 0, stream>>>(wv, wvb, 262144, 1.0f);
  cast_v4<<<1024, 256, 0, stream>>>(wo, wob, 262144, 1.0f);
  pack_mask<<<1024, 256, 0, stream>>>(mask, mb);
  transpose_cast<<<dim3(16, 16), 256, 0, stream>>>(wo, wotb);
  bias2<<<256, 256, 0, stream>>>(wo, bo, bo2);

  // W2 = Wo @ Wo  (A = Wo bf16, W-input = Wo^T in [N][K] layout)
  gemm_bt_64<<<dim3(16, 16), 256, 0, stream>>>(wob, wotb, W2b, 1024, 1024);

  const dim3 gg(64, 8);
  gemm_bt_a32<u16><<<gg, 256, 0, stream>>>(query, wqb, bq, Qb, 8192, 1024, 1024, qs);
  gemm_bt_a32<u16><<<gg, 256, 0, stream>>>(key_,  wkb, bk, Kb, 8192, 1024, 1024, 1.0f);
  gemm_bt_a32_vt<<<gg, 256, 0, stream>>>(value, wvb, bv, Vtb, 8192, 1024, 1024);

  attn_fwd<<<dim3(64, 16), 512, 0, stream>>>(Qb, Kb, Vtb, pos, mb, Xa);

  // out = Xa @ W2^T + bo2   (folds the doubled output linear)
  gemm_bt_a16<float><<<gg, 256, 0, stream>>>(Xa, W2b, bo2, (float*)d_out, 8192, 1024, 1024);
}